// Round 4
// baseline (309.306 us; speedup 1.0000x reference)
//
#include <hip/hip_runtime.h>
#include <cstdint>
#include <cstddef>

#define N_NODES 50000
#define N_EDGES 1600000
#define IN_FEAT 512
#define OUT_FEAT 128
#define NEG_SLOPE 0.01f
#define INV_TEMP 2.0f
#define PAD_DEG 128     // P(Poisson(32) >= 128) ~ e^-81: never

// two-phase CSR build
#define BUCKETS 400
#define BNODES 125      // nodes per bucket (400*125 = 50000)
#define BCAP 5000       // bucket capacity; Poisson(4000) max over 400 ~ 4300
#define A_BLOCKS 250
#define A_EPC (N_EDGES / A_BLOCKS)   // 6400 edges per block
#define A_G4 (A_EPC / 4)             // 1600 int4 groups

#define CONV_BLOCKS ((IN_FEAT * OUT_FEAT) / 256)       // 256
#define HCONV_BLOCKS ((N_NODES * IN_FEAT) / (256 * 8)) // 12500 (8 elems/thread)
#define GEMM_BLOCKS ((N_NODES + 63) / 64)              // 782 (tile 64x128)

typedef __attribute__((ext_vector_type(8))) short short8;
typedef __attribute__((ext_vector_type(4))) float f32x4;

#define GLOBAL_AS __attribute__((address_space(1)))
#define LDS_AS __attribute__((address_space(3)))

__device__ inline unsigned short f2bf(float x) {
    unsigned int u = __float_as_uint(x);
    unsigned int r = (u + 0x7fffu + ((u >> 16) & 1u)) >> 16;
    return (unsigned short)r;
}
__device__ inline float bf2f(unsigned short b) {
    return __uint_as_float(((unsigned int)b) << 16);
}

// ---------------- K2: fused {binA, hconv, convert_w} ----------------
// Three independent roles, block-partitioned. binA blocks first (latency-
// critical), then the bulk hconv stream (h fp32 -> hb bf16; its 153 MB of
// traffic hides under binA and leaves hb L3-resident for the GEMM), convW
// last. Requires bucket_cursor pre-zeroed (hipMemsetAsync before).

__global__ __launch_bounds__(256) void build_kernel(const float* __restrict__ W,
                                                    unsigned short* __restrict__ Wt,
                                                    const float* __restrict__ h,
                                                    unsigned short* __restrict__ hb,
                                                    const int* __restrict__ src,
                                                    const int* __restrict__ dst,
                                                    int* __restrict__ bucket_cursor,
                                                    int* __restrict__ binned) {
    __shared__ int cntL[BUCKETS];
    __shared__ int baseL[BUCKETS];

    if (blockIdx.x >= A_BLOCKS + HCONV_BLOCKS) {
        // ---- convert_w role: W (IN_FEAT x OUT_FEAT, row-major) -> Wt bf16 [n][k]
        int tid = (blockIdx.x - A_BLOCKS - HCONV_BLOCKS) * 256 + threadIdx.x;
        if (tid < IN_FEAT * OUT_FEAT) {
            int n = tid >> 9;
            int k = tid & 511;
            Wt[tid] = f2bf(W[k * OUT_FEAT + n]);
        }
        return;
    }

    if (blockIdx.x >= A_BLOCKS) {
        // ---- hconv role: h (fp32) -> hb (bf16), 8 elems/thread, streaming
        size_t base = ((size_t)(blockIdx.x - A_BLOCKS) * 256 + threadIdx.x) * 8;
        float4 v0 = *(const float4*)(h + base);
        float4 v1 = *(const float4*)(h + base + 4);
        short8 o;
        o[0] = (short)f2bf(v0.x); o[1] = (short)f2bf(v0.y);
        o[2] = (short)f2bf(v0.z); o[3] = (short)f2bf(v0.w);
        o[4] = (short)f2bf(v1.x); o[5] = (short)f2bf(v1.y);
        o[6] = (short)f2bf(v1.z); o[7] = (short)f2bf(v1.w);
        *(short8*)(hb + base) = o;
        return;
    }

    // ---- binA role: bin edges by bucket (LDS-counted; one device atomic per
    // (block, non-empty bucket) to reserve global ranges).
    int t = threadIdx.x;
    for (int i = t; i < BUCKETS; i += 256) cntL[i] = 0;
    __syncthreads();
    size_t ebase = (size_t)blockIdx.x * A_EPC;

    // pass 1: count per bucket (LDS atomics)
    for (int g = t; g < A_G4; g += 256) {
        int4 s4 = *(const int4*)(src + ebase + (size_t)g * 4);
#pragma unroll
        for (int j = 0; j < 4; ++j) {
            int s = (&s4.x)[j];
            atomicAdd(&cntL[s / BNODES], 1);
        }
    }
    __syncthreads();
    // reserve global ranges
    for (int i = t; i < BUCKETS; i += 256) {
        int c = cntL[i];
        baseL[i] = c ? atomicAdd(&bucket_cursor[i], c) : 0;
        cntL[i] = 0;
    }
    __syncthreads();
    // pass 2: write packed (src_local<<16)|dst into reserved slots
    for (int g = t; g < A_G4; g += 256) {
        int4 s4 = *(const int4*)(src + ebase + (size_t)g * 4);
        int4 d4 = *(const int4*)(dst + ebase + (size_t)g * 4);
#pragma unroll
        for (int j = 0; j < 4; ++j) {
            int s = (&s4.x)[j];
            int b = s / BNODES;
            int sl = s - b * BNODES;
            int pos = atomicAdd(&cntL[b], 1);
            int slot = baseL[b] + pos;
            if (slot < BCAP)
                binned[(size_t)b * BCAP + slot] = (sl << 16) | (&d4.x)[j];
        }
    }
}

// ---------------- K3: fused {mfma_gemm, binB} ----------------
// GEMM blocks FIRST (0..781) — latency-critical, launch immediately; binB
// blocks (782..1181) scatter binned -> padded CSR in the tail bubbles.
//
// v4 GEMM: A is pre-converted bf16 (hb, L3-warm from build_kernel), loaded
// directly as short8 — no f2bf chain, half the A bytes of v2/v3. B direct
// from L2-resident Wt (128 KB; the LDS slot lane L read in v2 was byte-
// identical to Wt[(nb*16+(L&15))*512 + k0+ksub*32+(L>>4)*8]). Zero LDS,
// zero barriers: waves run free, ~4.6 blocks/CU, per-step work is just
// 2 A-loads + 16 B-loads + 16 MFMAs.

__global__ __launch_bounds__(256) void gemm_binB_kernel(const unsigned short* __restrict__ hb,
                                                        const unsigned short* __restrict__ Wt,
                                                        const float* __restrict__ a_vec,
                                                        unsigned short* __restrict__ Whb,
                                                        float* __restrict__ s1,
                                                        float* __restrict__ s2,
                                                        const int* __restrict__ bucket_cursor,
                                                        const int* __restrict__ binned,
                                                        int* __restrict__ cnt,
                                                        int* __restrict__ csr) {
    __shared__ int cL[BNODES];   // binB only; gemm role uses no LDS

    if (blockIdx.x >= GEMM_BLOCKS) {
        // ---- binB role: bucket -> padded CSR
        int b = blockIdx.x - GEMM_BLOCKS;
        int t = threadIdx.x;
        if (t < BNODES) cL[t] = 0;
        __syncthreads();
        int m = min(bucket_cursor[b], BCAP);
        const int* bp = binned + (size_t)b * BCAP;
        int n0 = b * BNODES;
        for (int i = t; i < m; i += 256) {
            int p = bp[i];
            int sl = p >> 16;
            int d = p & 0xFFFF;
            int pos = atomicAdd(&cL[sl], 1);
            if (pos < PAD_DEG) csr[(size_t)(n0 + sl) * PAD_DEG + pos] = d;
        }
        __syncthreads();
        if (t < BNODES) cnt[n0 + t] = min(cL[t], PAD_DEG);
        return;
    }

    // ---- gemm role: tile 64x128, 4 waves (16 rows each)
    int bid = blockIdx.x;
    int t = threadIdx.x;
    int w = t >> 6;
    int L = t & 63;
    int m0 = bid * 64;
    int col0 = L & 15;
    int kq = (L >> 4) * 8;

    int arow = m0 + w * 16 + col0;
    bool arow_ok = arow < N_NODES;
    const unsigned short* hrow = hb + (size_t)arow * IN_FEAT;

    // per-lane B base: row (nb*16 + col0), k-slice kq
    const unsigned short* bbase = Wt + (size_t)col0 * IN_FEAT + kq;

    f32x4 acc[8];
#pragma unroll
    for (int nb = 0; nb < 8; ++nb) acc[nb] = (f32x4){0.f, 0.f, 0.f, 0.f};

    // A prologue: k-step 0
    short8 af[2];
#pragma unroll
    for (int c = 0; c < 2; ++c) af[c] = (short8){0, 0, 0, 0, 0, 0, 0, 0};
    if (arow_ok) {
        af[0] = *(const short8*)(hrow + kq);
        af[1] = *(const short8*)(hrow + 32 + kq);
    }

#pragma unroll
    for (int it = 0; it < 8; ++it) {
        const int k0 = it * 64;

        // next step's A loads issued before this step's MFMAs (no barrier
        // anywhere -> they stay in flight under B loads + MFMAs)
        short8 afn[2];
#pragma unroll
        for (int c = 0; c < 2; ++c) afn[c] = (short8){0, 0, 0, 0, 0, 0, 0, 0};
        if (it < 7 && arow_ok) {
            afn[0] = *(const short8*)(hrow + (it + 1) * 64 + kq);
            afn[1] = *(const short8*)(hrow + (it + 1) * 64 + 32 + kq);
        }

        // B-fragments for this step: direct from L2-resident Wt
        short8 bfr[2][8];   // [ksub][nb]
#pragma unroll
        for (int ksub = 0; ksub < 2; ++ksub)
#pragma unroll
            for (int nb = 0; nb < 8; ++nb)
                bfr[ksub][nb] =
                    *(const short8*)(bbase + (size_t)nb * 16 * IN_FEAT + k0 + ksub * 32);

#pragma unroll
        for (int ksub = 0; ksub < 2; ++ksub)
#pragma unroll
            for (int nb = 0; nb < 8; ++nb)
                acc[nb] = __builtin_amdgcn_mfma_f32_16x16x32_bf16(af[ksub], bfr[ksub][nb],
                                                                  acc[nb], 0, 0, 0);

        af[0] = afn[0];
        af[1] = afn[1];
    }

    // epilogue: store Whb (bf16) + fused s1/s2 dot products
    float a1c[8], a2c[8];
#pragma unroll
    for (int nb = 0; nb < 8; ++nb) {
        a1c[nb] = a_vec[nb * 16 + col0];
        a2c[nb] = a_vec[128 + nb * 16 + col0];
    }

    int rbase = m0 + w * 16 + (L >> 4) * 4;
#pragma unroll
    for (int r = 0; r < 4; ++r) {
        int row = rbase + r;
        bool ok = row < N_NODES;
        float p1 = 0.f, p2 = 0.f;
        if (ok) {
            unsigned short* orow = Whb + (size_t)row * OUT_FEAT;
#pragma unroll
            for (int nb = 0; nb < 8; ++nb) {
                float v = acc[nb][r];
                orow[nb * 16 + col0] = f2bf(v);
                p1 = fmaf(v, a1c[nb], p1);
                p2 = fmaf(v, a2c[nb], p2);
            }
        }
#pragma unroll
        for (int off = 8; off > 0; off >>= 1) {
            p1 += __shfl_xor(p1, off, 64);
            p2 += __shfl_xor(p2, off, 64);
        }
        if (ok && col0 == 0) {
            s1[row] = p1;
            s2[row] = p2;
        }
    }
}

// ---------------- per-node softmax + aggregation ----------------
// One wave per node; lane group g = lane>>4 handles edge jj+g; lane covers
// features (lane&15)*8..+7 via one 16B short8 load -> 4 rows (1KB) per wave
// instruction. Invalid edges contribute p=0 (their source lane's ex is 0).

__global__ __launch_bounds__(256) void node_kernel(const unsigned short* __restrict__ Whb,
                                                   const float* __restrict__ s1,
                                                   const float* __restrict__ s2,
                                                   const int* __restrict__ cnt,
                                                   const int* __restrict__ csr,
                                                   float* __restrict__ out) {
    int lane = threadIdx.x & 63;
    int w = threadIdx.x >> 6;
    int n = blockIdx.x * 4 + w;
    if (n >= N_NODES) return;
    int deg = cnt[n];
    size_t start = (size_t)n * PAD_DEG;
    int g = lane >> 4;
    int fo = lane & 15;

    float accv[8];
#pragma unroll
    for (int f = 0; f < 8; ++f) accv[f] = 0.f;
    float inv = 0.f;

    if (deg > 0) {
        float s1n = s1[n];
        int d0 = 0, d1 = 0;
        float ex0 = 0.f, ex1 = 0.f;
        if (lane < deg) {
            d0 = csr[start + lane];
            float ev = s1n + s2[d0];
            ev = ev >= 0.f ? ev : NEG_SLOPE * ev;
            ex0 = __expf(ev * INV_TEMP);
        }
        if (lane + 64 < deg) {
            d1 = csr[start + lane + 64];
            float ev = s1n + s2[d1];
            ev = ev >= 0.f ? ev : NEG_SLOPE * ev;
            ex1 = __expf(ev * INV_TEMP);
        }
        float denom = ex0 + ex1;
#pragma unroll
        for (int off = 32; off > 0; off >>= 1) denom += __shfl_xor(denom, off, 64);
        inv = 1.0f / denom;

#pragma unroll 2
        for (int jj = 0; jj < deg; jj += 4) {
            int e = jj + g;
            bool hi = jj >= 64;             // wave-uniform
            float exs = hi ? ex1 : ex0;
            int dsel = hi ? d1 : d0;
            float p = __shfl(exs, e & 63, 64);
            int dd = __shfl(dsel, e & 63, 64);
            short8 row = *(const short8*)(Whb + (size_t)dd * OUT_FEAT + fo * 8);
#pragma unroll
            for (int f = 0; f < 8; ++f)
                accv[f] = fmaf(p, bf2f((unsigned short)row[f]), accv[f]);
        }
#pragma unroll
        for (int f = 0; f < 8; ++f) {
            accv[f] += __shfl_xor(accv[f], 16, 64);
            accv[f] += __shfl_xor(accv[f], 32, 64);
        }
    }

    if (g == 0) {
        float* orow = out + (size_t)n * OUT_FEAT + fo * 8;
        float4 o0, o1;
        o0.x = fmaxf(accv[0] * inv, 0.f); o0.y = fmaxf(accv[1] * inv, 0.f);
        o0.z = fmaxf(accv[2] * inv, 0.f); o0.w = fmaxf(accv[3] * inv, 0.f);
        o1.x = fmaxf(accv[4] * inv, 0.f); o1.y = fmaxf(accv[5] * inv, 0.f);
        o1.z = fmaxf(accv[6] * inv, 0.f); o1.w = fmaxf(accv[7] * inv, 0.f);
        *(float4*)(orow) = o0;
        *(float4*)(orow + 4) = o1;
    }
}

// ---------------- launch ----------------

extern "C" void kernel_launch(void* const* d_in, const int* in_sizes, int n_in,
                              void* d_out, int out_size, void* d_ws, size_t ws_size,
                              hipStream_t stream) {
    const float* h = (const float*)d_in[0];
    const float* W = (const float*)d_in[1];
    const float* a = (const float*)d_in[2];
    const int* edge = (const int*)d_in[3];
    const int* src = edge;
    const int* dst = edge + N_EDGES;
    float* out = (float*)d_out;

    char* ws = (char*)d_ws;
    size_t off = 0;
    auto alloc = [&](size_t bytes) -> void* {
        void* p = ws + off;
        off = (off + bytes + 255) & ~(size_t)255;
        return p;
    };
    unsigned short* Whb = (unsigned short*)alloc((size_t)N_NODES * OUT_FEAT * sizeof(unsigned short));
    float* s1 = (float*)alloc((size_t)N_NODES * sizeof(float));
    float* s2 = (float*)alloc((size_t)N_NODES * sizeof(float));
    int* cnt = (int*)alloc((size_t)N_NODES * sizeof(int));
    int* csr = (int*)alloc((size_t)N_NODES * PAD_DEG * sizeof(int));
    unsigned short* Wt = (unsigned short*)alloc((size_t)IN_FEAT * OUT_FEAT * sizeof(unsigned short));
    unsigned short* hb = (unsigned short*)alloc((size_t)N_NODES * IN_FEAT * sizeof(unsigned short));
    int* bucket_cursor = (int*)alloc((size_t)BUCKETS * sizeof(int));
    int* binned = (int*)alloc((size_t)BUCKETS * BCAP * sizeof(int));

    hipMemsetAsync(bucket_cursor, 0, BUCKETS * sizeof(int), stream);
    build_kernel<<<A_BLOCKS + HCONV_BLOCKS + CONV_BLOCKS, 256, 0, stream>>>(
        W, Wt, h, hb, src, dst, bucket_cursor, binned);
    gemm_binB_kernel<<<GEMM_BLOCKS + BUCKETS, 256, 0, stream>>>(hb, Wt, a, Whb, s1, s2,
                                                                bucket_cursor, binned, cnt, csr);
    node_kernel<<<(N_NODES + 3) / 4, 256, 0, stream>>>(Whb, s1, s2, cnt, csr, out);
}

// Round 5
// 297.327 us; speedup vs baseline: 1.0403x; 1.0403x over previous
//
#include <hip/hip_runtime.h>
#include <cstdint>
#include <cstddef>

#define N_NODES 50000
#define N_EDGES 1600000
#define IN_FEAT 512
#define OUT_FEAT 128
#define NEG_SLOPE 0.01f
#define INV_TEMP 2.0f
#define PAD_DEG 128     // P(Poisson(32) >= 128) ~ e^-81: never

// two-phase CSR build
#define BUCKETS 400
#define BNODES 125      // nodes per bucket (400*125 = 50000)
#define BCAP 5000       // bucket capacity; Poisson(4000) max over 400 ~ 4300
#define A_BLOCKS 250
#define A_EPC (N_EDGES / A_BLOCKS)   // 6400 edges per block
#define A_G4 (A_EPC / 4)             // 1600 int4 groups

#define CONV_BLOCKS ((IN_FEAT * OUT_FEAT) / 256)   // 256
#define GEMM_BLOCKS ((N_NODES + 63) / 64)          // 782 (tile 64x128)

typedef __attribute__((ext_vector_type(8))) short short8;
typedef __attribute__((ext_vector_type(4))) float f32x4;

#define GLOBAL_AS __attribute__((address_space(1)))
#define LDS_AS __attribute__((address_space(3)))

__device__ inline unsigned short f2bf(float x) {
    unsigned int u = __float_as_uint(x);
    unsigned int r = (u + 0x7fffu + ((u >> 16) & 1u)) >> 16;
    return (unsigned short)r;
}
__device__ inline float bf2f(unsigned short b) {
    return __uint_as_float(((unsigned int)b) << 16);
}

// ---------------- K2: fused {binA, convert_w} ----------------
// (hconv REVERTED: round-4 counters showed it cost +40us in build while the
// GEMM didn't speed up — bytes were not the GEMM's problem.)
// Requires bucket_cursor pre-zeroed (hipMemsetAsync before).

__global__ __launch_bounds__(256) void build_kernel(const float* __restrict__ W,
                                                    unsigned short* __restrict__ Wt,
                                                    const int* __restrict__ src,
                                                    const int* __restrict__ dst,
                                                    int* __restrict__ bucket_cursor,
                                                    int* __restrict__ binned) {
    __shared__ int cntL[BUCKETS];
    __shared__ int baseL[BUCKETS];

    if (blockIdx.x >= A_BLOCKS) {
        // ---- convert_w role: W (IN_FEAT x OUT_FEAT, row-major) -> Wt bf16 [n][k]
        int tid = (blockIdx.x - A_BLOCKS) * 256 + threadIdx.x;
        if (tid < IN_FEAT * OUT_FEAT) {
            int n = tid >> 9;
            int k = tid & 511;
            Wt[tid] = f2bf(W[k * OUT_FEAT + n]);
        }
        return;
    }

    // ---- binA role: bin edges by bucket (LDS-counted; one device atomic per
    // (block, non-empty bucket) to reserve global ranges).
    int t = threadIdx.x;
    for (int i = t; i < BUCKETS; i += 256) cntL[i] = 0;
    __syncthreads();
    size_t ebase = (size_t)blockIdx.x * A_EPC;

    // pass 1: count per bucket (LDS atomics)
    for (int g = t; g < A_G4; g += 256) {
        int4 s4 = *(const int4*)(src + ebase + (size_t)g * 4);
#pragma unroll
        for (int j = 0; j < 4; ++j) {
            int s = (&s4.x)[j];
            atomicAdd(&cntL[s / BNODES], 1);
        }
    }
    __syncthreads();
    // reserve global ranges
    for (int i = t; i < BUCKETS; i += 256) {
        int c = cntL[i];
        baseL[i] = c ? atomicAdd(&bucket_cursor[i], c) : 0;
        cntL[i] = 0;
    }
    __syncthreads();
    // pass 2: write packed (src_local<<16)|dst into reserved slots
    for (int g = t; g < A_G4; g += 256) {
        int4 s4 = *(const int4*)(src + ebase + (size_t)g * 4);
        int4 d4 = *(const int4*)(dst + ebase + (size_t)g * 4);
#pragma unroll
        for (int j = 0; j < 4; ++j) {
            int s = (&s4.x)[j];
            int b = s / BNODES;
            int sl = s - b * BNODES;
            int pos = atomicAdd(&cntL[b], 1);
            int slot = baseL[b] + pos;
            if (slot < BCAP)
                binned[(size_t)b * BCAP + slot] = (sl << 16) | (&d4.x)[j];
        }
    }
}

// ---------------- K3: MFMA GEMM standalone (de-fused for rocprof
// visibility — rounds 2-4 suggest the binB role was masking it).
// Barrier-free / LDS-free: A fp32 -> in-register bf16 convert; B direct from
// L2-resident Wt (128 KB). Tile 64x128, 4 waves, 782 blocks. ----------------

__global__ __launch_bounds__(256) void gemm_kernel(const float* __restrict__ h,
                                                   const unsigned short* __restrict__ Wt,
                                                   const float* __restrict__ a_vec,
                                                   unsigned short* __restrict__ Whb,
                                                   float* __restrict__ s1,
                                                   float* __restrict__ s2) {
    int bid = blockIdx.x;
    int t = threadIdx.x;
    int w = t >> 6;
    int L = t & 63;
    int m0 = bid * 64;
    int col0 = L & 15;
    int kq = (L >> 4) * 8;

    int arow = m0 + w * 16 + col0;
    bool arow_ok = arow < N_NODES;
    const float* arp = h + (size_t)arow * IN_FEAT + kq;

    // per-lane B base: row (nb*16 + col0), k-slice kq
    const unsigned short* bbase = Wt + (size_t)col0 * IN_FEAT + kq;

    f32x4 acc[8];
#pragma unroll
    for (int nb = 0; nb < 8; ++nb) acc[nb] = (f32x4){0.f, 0.f, 0.f, 0.f};

    // A prologue: k-step 0
    float4 av[2][2];
#pragma unroll
    for (int c = 0; c < 2; ++c) {
        av[c][0] = make_float4(0.f, 0.f, 0.f, 0.f);
        av[c][1] = make_float4(0.f, 0.f, 0.f, 0.f);
    }
    if (arow_ok) {
        av[0][0] = *(const float4*)(arp);
        av[0][1] = *(const float4*)(arp + 4);
        av[1][0] = *(const float4*)(arp + 32);
        av[1][1] = *(const float4*)(arp + 36);
    }

#pragma unroll
    for (int it = 0; it < 8; ++it) {
        const int k0 = it * 64;

        // next step's A loads issued before this step's MFMAs (no barrier
        // anywhere -> they stay in flight under B loads + MFMAs)
        float4 avn[2][2];
#pragma unroll
        for (int c = 0; c < 2; ++c) {
            avn[c][0] = make_float4(0.f, 0.f, 0.f, 0.f);
            avn[c][1] = make_float4(0.f, 0.f, 0.f, 0.f);
        }
        if (it < 7 && arow_ok) {
            const float* p = arp + (it + 1) * 64;
            avn[0][0] = *(const float4*)(p);
            avn[0][1] = *(const float4*)(p + 4);
            avn[1][0] = *(const float4*)(p + 32);
            avn[1][1] = *(const float4*)(p + 36);
        }

        // B-fragments for this step: direct from L2-resident Wt
        short8 bfr[2][8];   // [ksub][nb]
#pragma unroll
        for (int ksub = 0; ksub < 2; ++ksub)
#pragma unroll
            for (int nb = 0; nb < 8; ++nb)
                bfr[ksub][nb] =
                    *(const short8*)(bbase + (size_t)nb * 16 * IN_FEAT + k0 + ksub * 32);

        // convert this step's A fragments in-register
        short8 af[2];
#pragma unroll
        for (int c = 0; c < 2; ++c) {
            short8 v;
            v[0] = (short)f2bf(av[c][0].x); v[1] = (short)f2bf(av[c][0].y);
            v[2] = (short)f2bf(av[c][0].z); v[3] = (short)f2bf(av[c][0].w);
            v[4] = (short)f2bf(av[c][1].x); v[5] = (short)f2bf(av[c][1].y);
            v[6] = (short)f2bf(av[c][1].z); v[7] = (short)f2bf(av[c][1].w);
            af[c] = v;
        }

#pragma unroll
        for (int ksub = 0; ksub < 2; ++ksub)
#pragma unroll
            for (int nb = 0; nb < 8; ++nb)
                acc[nb] = __builtin_amdgcn_mfma_f32_16x16x32_bf16(af[ksub], bfr[ksub][nb],
                                                                  acc[nb], 0, 0, 0);

#pragma unroll
        for (int c = 0; c < 2; ++c) {
            av[c][0] = avn[c][0];
            av[c][1] = avn[c][1];
        }
    }

    // epilogue: store Whb (bf16) + fused s1/s2 dot products
    float a1c[8], a2c[8];
#pragma unroll
    for (int nb = 0; nb < 8; ++nb) {
        a1c[nb] = a_vec[nb * 16 + col0];
        a2c[nb] = a_vec[128 + nb * 16 + col0];
    }

    int rbase = m0 + w * 16 + (L >> 4) * 4;
#pragma unroll
    for (int r = 0; r < 4; ++r) {
        int row = rbase + r;
        bool ok = row < N_NODES;
        float p1 = 0.f, p2 = 0.f;
        if (ok) {
            unsigned short* orow = Whb + (size_t)row * OUT_FEAT;
#pragma unroll
            for (int nb = 0; nb < 8; ++nb) {
                float v = acc[nb][r];
                orow[nb * 16 + col0] = f2bf(v);
                p1 = fmaf(v, a1c[nb], p1);
                p2 = fmaf(v, a2c[nb], p2);
            }
        }
#pragma unroll
        for (int off = 8; off > 0; off >>= 1) {
            p1 += __shfl_xor(p1, off, 64);
            p2 += __shfl_xor(p2, off, 64);
        }
        if (ok && col0 == 0) {
            s1[row] = p1;
            s2[row] = p2;
        }
    }
}

// ---------------- K4: binB standalone (de-fused for visibility) ----------------

__global__ __launch_bounds__(256) void binB_kernel(const int* __restrict__ bucket_cursor,
                                                   const int* __restrict__ binned,
                                                   int* __restrict__ cnt,
                                                   int* __restrict__ csr) {
    __shared__ int cL[BNODES];
    int b = blockIdx.x;
    int t = threadIdx.x;
    if (t < BNODES) cL[t] = 0;
    __syncthreads();
    int m = min(bucket_cursor[b], BCAP);
    const int* bp = binned + (size_t)b * BCAP;
    int n0 = b * BNODES;
    for (int i = t; i < m; i += 256) {
        int p = bp[i];
        int sl = p >> 16;
        int d = p & 0xFFFF;
        int pos = atomicAdd(&cL[sl], 1);
        if (pos < PAD_DEG) csr[(size_t)(n0 + sl) * PAD_DEG + pos] = d;
    }
    __syncthreads();
    if (t < BNODES) cnt[n0 + t] = min(cL[t], PAD_DEG);
}

// ---------------- K5: per-node softmax + aggregation ----------------
// One wave per node. v2: 8 edges per iteration (two lane-group passes) with
// unroll 2 -> 4 independent Whb row-gathers in flight (was 2), to cover the
// ~400-700cy L2/L3 gather latency.

__global__ __launch_bounds__(256) void node_kernel(const unsigned short* __restrict__ Whb,
                                                   const float* __restrict__ s1,
                                                   const float* __restrict__ s2,
                                                   const int* __restrict__ cnt,
                                                   const int* __restrict__ csr,
                                                   float* __restrict__ out) {
    int lane = threadIdx.x & 63;
    int w = threadIdx.x >> 6;
    int n = blockIdx.x * 4 + w;
    if (n >= N_NODES) return;
    int deg = cnt[n];
    size_t start = (size_t)n * PAD_DEG;
    int g = lane >> 4;
    int fo = lane & 15;

    float accv[8];
#pragma unroll
    for (int f = 0; f < 8; ++f) accv[f] = 0.f;
    float inv = 0.f;

    if (deg > 0) {
        float s1n = s1[n];
        int d0 = 0, d1 = 0;
        float ex0 = 0.f, ex1 = 0.f;
        if (lane < deg) {
            d0 = csr[start + lane];
            float ev = s1n + s2[d0];
            ev = ev >= 0.f ? ev : NEG_SLOPE * ev;
            ex0 = __expf(ev * INV_TEMP);
        }
        if (lane + 64 < deg) {
            d1 = csr[start + lane + 64];
            float ev = s1n + s2[d1];
            ev = ev >= 0.f ? ev : NEG_SLOPE * ev;
            ex1 = __expf(ev * INV_TEMP);
        }
        float denom = ex0 + ex1;
#pragma unroll
        for (int off = 32; off > 0; off >>= 1) denom += __shfl_xor(denom, off, 64);
        inv = 1.0f / denom;

        // 8 edges per iteration: e0 = jj+g, e1 = jj+4+g. Edges >= deg
        // contribute p=0 (their source lane's ex is 0), so overrun is safe.
#pragma unroll 2
        for (int jj = 0; jj < deg; jj += 8) {
            int e0 = jj + g;
            int e1 = jj + 4 + g;
            bool hi0 = jj >= 64;                 // wave-uniform
            bool hi1 = (jj + 4) >= 64;           // wave-uniform
            float p0 = __shfl(hi0 ? ex1 : ex0, e0 & 63, 64);
            int dd0 = __shfl(hi0 ? d1 : d0, e0 & 63, 64);
            float p1 = __shfl(hi1 ? ex1 : ex0, e1 & 63, 64);
            int dd1 = __shfl(hi1 ? d1 : d0, e1 & 63, 64);
            short8 row0 = *(const short8*)(Whb + (size_t)dd0 * OUT_FEAT + fo * 8);
            short8 row1 = *(const short8*)(Whb + (size_t)dd1 * OUT_FEAT + fo * 8);
#pragma unroll
            for (int f = 0; f < 8; ++f)
                accv[f] = fmaf(p0, bf2f((unsigned short)row0[f]), accv[f]);
#pragma unroll
            for (int f = 0; f < 8; ++f)
                accv[f] = fmaf(p1, bf2f((unsigned short)row1[f]), accv[f]);
        }
#pragma unroll
        for (int f = 0; f < 8; ++f) {
            accv[f] += __shfl_xor(accv[f], 16, 64);
            accv[f] += __shfl_xor(accv[f], 32, 64);
        }
    }

    if (g == 0) {
        float* orow = out + (size_t)n * OUT_FEAT + fo * 8;
        float4 o0, o1;
        o0.x = fmaxf(accv[0] * inv, 0.f); o0.y = fmaxf(accv[1] * inv, 0.f);
        o0.z = fmaxf(accv[2] * inv, 0.f); o0.w = fmaxf(accv[3] * inv, 0.f);
        o1.x = fmaxf(accv[4] * inv, 0.f); o1.y = fmaxf(accv[5] * inv, 0.f);
        o1.z = fmaxf(accv[6] * inv, 0.f); o1.w = fmaxf(accv[7] * inv, 0.f);
        *(float4*)(orow) = o0;
        *(float4*)(orow + 4) = o1;
    }
}

// ---------------- launch ----------------

extern "C" void kernel_launch(void* const* d_in, const int* in_sizes, int n_in,
                              void* d_out, int out_size, void* d_ws, size_t ws_size,
                              hipStream_t stream) {
    const float* h = (const float*)d_in[0];
    const float* W = (const float*)d_in[1];
    const float* a = (const float*)d_in[2];
    const int* edge = (const int*)d_in[3];
    const int* src = edge;
    const int* dst = edge + N_EDGES;
    float* out = (float*)d_out;

    char* ws = (char*)d_ws;
    size_t off = 0;
    auto alloc = [&](size_t bytes) -> void* {
        void* p = ws + off;
        off = (off + bytes + 255) & ~(size_t)255;
        return p;
    };
    unsigned short* Whb = (unsigned short*)alloc((size_t)N_NODES * OUT_FEAT * sizeof(unsigned short));
    float* s1 = (float*)alloc((size_t)N_NODES * sizeof(float));
    float* s2 = (float*)alloc((size_t)N_NODES * sizeof(float));
    int* cnt = (int*)alloc((size_t)N_NODES * sizeof(int));
    int* csr = (int*)alloc((size_t)N_NODES * PAD_DEG * sizeof(int));
    unsigned short* Wt = (unsigned short*)alloc((size_t)IN_FEAT * OUT_FEAT * sizeof(unsigned short));
    int* bucket_cursor = (int*)alloc((size_t)BUCKETS * sizeof(int));
    int* binned = (int*)alloc((size_t)BUCKETS * BCAP * sizeof(int));

    hipMemsetAsync(bucket_cursor, 0, BUCKETS * sizeof(int), stream);
    build_kernel<<<A_BLOCKS + CONV_BLOCKS, 256, 0, stream>>>(W, Wt, src, dst, bucket_cursor, binned);
    gemm_kernel<<<GEMM_BLOCKS, 256, 0, stream>>>(h, Wt, a, Whb, s1, s2);
    binB_kernel<<<BUCKETS, 256, 0, stream>>>(bucket_cursor, binned, cnt, csr);
    node_kernel<<<(N_NODES + 3) / 4, 256, 0, stream>>>(Whb, s1, s2, cnt, csr, out);
}

// Round 6
// 266.566 us; speedup vs baseline: 1.1603x; 1.1154x over previous
//
#include <hip/hip_runtime.h>
#include <cstdint>
#include <cstddef>

#define N_NODES 50000
#define N_EDGES 1600000
#define IN_FEAT 512
#define OUT_FEAT 128
#define NEG_SLOPE 0.01f
#define INV_TEMP 2.0f
#define PAD_DEG 128     // P(Poisson(32) >= 128) ~ e^-81: never

// two-phase CSR build
#define BUCKETS 400
#define BNODES 125      // nodes per bucket (400*125 = 50000)
#define BCAP 5000       // bucket capacity; Poisson(4000) max over 400 ~ 4300
#define A_BLOCKS 500    // v6: 250 -> 500 (binA was <1 block/CU, ~60us; device
                        // atomics only grow to <=200K, far from the 1.6M wall)
#define A_EPC (N_EDGES / A_BLOCKS)   // 3200 edges per block
#define A_G4 (A_EPC / 4)             // 800 int4 groups

#define CONV_BLOCKS ((IN_FEAT * OUT_FEAT) / 256)   // 256
#define GEMM_BLOCKS ((N_NODES + 63) / 64)          // 782 (tile 64x128)

typedef __attribute__((ext_vector_type(8))) short short8;
typedef __attribute__((ext_vector_type(4))) float f32x4;

#define GLOBAL_AS __attribute__((address_space(1)))
#define LDS_AS __attribute__((address_space(3)))

__device__ inline unsigned short f2bf(float x) {
    unsigned int u = __float_as_uint(x);
    unsigned int r = (u + 0x7fffu + ((u >> 16) & 1u)) >> 16;
    return (unsigned short)r;
}
__device__ inline float bf2f(unsigned short b) {
    return __uint_as_float(((unsigned int)b) << 16);
}

// ---------------- K2: fused {binA, convert_w} ----------------
// Requires bucket_cursor pre-zeroed (hipMemsetAsync before this kernel).

__global__ __launch_bounds__(256) void build_kernel(const float* __restrict__ W,
                                                    unsigned short* __restrict__ Wt,
                                                    const int* __restrict__ src,
                                                    const int* __restrict__ dst,
                                                    int* __restrict__ bucket_cursor,
                                                    int* __restrict__ binned) {
    __shared__ int cntL[BUCKETS];
    __shared__ int baseL[BUCKETS];

    if (blockIdx.x >= A_BLOCKS) {
        // ---- convert_w role: W (IN_FEAT x OUT_FEAT, row-major) -> Wt bf16 [n][k]
        int tid = (blockIdx.x - A_BLOCKS) * 256 + threadIdx.x;
        if (tid < IN_FEAT * OUT_FEAT) {
            int n = tid >> 9;
            int k = tid & 511;
            Wt[tid] = f2bf(W[k * OUT_FEAT + n]);
        }
        return;
    }

    // ---- binA role: bin edges by bucket (LDS-counted; one device atomic per
    // (block, non-empty bucket) to reserve global ranges).
    int t = threadIdx.x;
    for (int i = t; i < BUCKETS; i += 256) cntL[i] = 0;
    __syncthreads();
    size_t ebase = (size_t)blockIdx.x * A_EPC;

    // pass 1: count per bucket (LDS atomics)
    for (int g = t; g < A_G4; g += 256) {
        int4 s4 = *(const int4*)(src + ebase + (size_t)g * 4);
#pragma unroll
        for (int j = 0; j < 4; ++j) {
            int s = (&s4.x)[j];
            atomicAdd(&cntL[s / BNODES], 1);
        }
    }
    __syncthreads();
    // reserve global ranges
    for (int i = t; i < BUCKETS; i += 256) {
        int c = cntL[i];
        baseL[i] = c ? atomicAdd(&bucket_cursor[i], c) : 0;
        cntL[i] = 0;
    }
    __syncthreads();
    // pass 2: write packed (src_local<<16)|dst into reserved slots
    for (int g = t; g < A_G4; g += 256) {
        int4 s4 = *(const int4*)(src + ebase + (size_t)g * 4);
        int4 d4 = *(const int4*)(dst + ebase + (size_t)g * 4);
#pragma unroll
        for (int j = 0; j < 4; ++j) {
            int s = (&s4.x)[j];
            int b = s / BNODES;
            int sl = s - b * BNODES;
            int pos = atomicAdd(&cntL[b], 1);
            int slot = baseL[b] + pos;
            if (slot < BCAP)
                binned[(size_t)b * BCAP + slot] = (sl << 16) | (&d4.x)[j];
        }
    }
}

// ---------------- K3: fused {binB, mfma_gemm} ----------------
// REVERTED to round-2 structure (measured 63.9us fused, vs 87.6us for the
// round-5 barrier-free direct-B version: per-lane scattered B loads were
// 16x64B segments per instruction and 4x redundant across waves — LDS
// sharing of B via global_load_lds was doing real work).
// binB blocks (0..399) scatter binned -> padded CSR; gemm blocks (400..1181)
// run the MFMA GEMM with A in registers, B double-buffered in LDS, one
// barrier per k-step.

__global__ __launch_bounds__(256) void gemm_binB_kernel(const float* __restrict__ h,
                                                        const unsigned short* __restrict__ Wt,
                                                        const float* __restrict__ a_vec,
                                                        unsigned short* __restrict__ Whb,
                                                        float* __restrict__ s1,
                                                        float* __restrict__ s2,
                                                        const int* __restrict__ bucket_cursor,
                                                        const int* __restrict__ binned,
                                                        int* __restrict__ cnt,
                                                        int* __restrict__ csr) {
    __shared__ unsigned short lB[2][8 * 2 * 64 * 8];   // 32 KB (gemm); front 500B = binB cL

    if (blockIdx.x < BUCKETS) {
        // ---- binB role: bucket -> padded CSR
        int* cL = (int*)&lB[0][0];
        int b = blockIdx.x;
        int t = threadIdx.x;
        if (t < BNODES) cL[t] = 0;
        __syncthreads();
        int m = min(bucket_cursor[b], BCAP);
        const int* bp = binned + (size_t)b * BCAP;
        int n0 = b * BNODES;
        for (int i = t; i < m; i += 256) {
            int p = bp[i];
            int sl = p >> 16;
            int d = p & 0xFFFF;
            int pos = atomicAdd(&cL[sl], 1);
            if (pos < PAD_DEG) csr[(size_t)(n0 + sl) * PAD_DEG + pos] = d;
        }
        __syncthreads();
        if (t < BNODES) cnt[n0 + t] = min(cL[t], PAD_DEG);
        return;
    }

    // ---- gemm role: tile 64x128, 4 waves, BK=64
    int bid = blockIdx.x - BUCKETS;
    int t = threadIdx.x;
    int w = t >> 6;
    int L = t & 63;
    int m0 = bid * 64;

    int arow = m0 + w * 16 + (L & 15);
    bool arow_ok = arow < N_NODES;
    int kq = (L >> 4) * 8;
    const float* arp = h + (size_t)arow * IN_FEAT + kq;

    f32x4 acc[8];
#pragma unroll
    for (int i = 0; i < 8; ++i) acc[i] = (f32x4){0.f, 0.f, 0.f, 0.f};

    auto stageB = [&](int buf, int k0) {
#pragma unroll
        for (int c = 0; c < 4; ++c) {
            int nb = w * 2 + (c >> 1);
            int ksub = c & 1;
            const GLOBAL_AS unsigned short* g =
                (const GLOBAL_AS unsigned short*)(Wt + (size_t)(nb * 16 + (L & 15)) * IN_FEAT +
                                                  (k0 + ksub * 32 + kq));
            LDS_AS unsigned short* lp = (LDS_AS unsigned short*)(&lB[buf][(nb * 2 + ksub) * 512]);
            __builtin_amdgcn_global_load_lds((const GLOBAL_AS void*)g, (LDS_AS void*)lp, 16, 0, 0);
        }
    };

    float4 av[2][2];
#pragma unroll
    for (int c = 0; c < 2; ++c) {
        av[c][0] = make_float4(0.f, 0.f, 0.f, 0.f);
        av[c][1] = make_float4(0.f, 0.f, 0.f, 0.f);
    }
    if (arow_ok) {
        av[0][0] = *(const float4*)(arp);
        av[0][1] = *(const float4*)(arp + 4);
        av[1][0] = *(const float4*)(arp + 32);
        av[1][1] = *(const float4*)(arp + 36);
    }
    stageB(0, 0);
    __syncthreads();   // vmcnt drain: buf0 ready

#pragma unroll
    for (int it = 0; it < 8; ++it) {
        const int buf = it & 1;

        if (it < 7) stageB(buf ^ 1, (it + 1) * 64);

        float4 avn[2][2];
#pragma unroll
        for (int c = 0; c < 2; ++c) {
            avn[c][0] = make_float4(0.f, 0.f, 0.f, 0.f);
            avn[c][1] = make_float4(0.f, 0.f, 0.f, 0.f);
        }
        if (it < 7 && arow_ok) {
            const float* p = arp + (it + 1) * 64;
            avn[0][0] = *(const float4*)(p);
            avn[0][1] = *(const float4*)(p + 4);
            avn[1][0] = *(const float4*)(p + 32);
            avn[1][1] = *(const float4*)(p + 36);
        }

        short8 af[2];
#pragma unroll
        for (int c = 0; c < 2; ++c) {
            short8 v;
            v[0] = (short)f2bf(av[c][0].x); v[1] = (short)f2bf(av[c][0].y);
            v[2] = (short)f2bf(av[c][0].z); v[3] = (short)f2bf(av[c][0].w);
            v[4] = (short)f2bf(av[c][1].x); v[5] = (short)f2bf(av[c][1].y);
            v[6] = (short)f2bf(av[c][1].z); v[7] = (short)f2bf(av[c][1].w);
            af[c] = v;
        }

#pragma unroll
        for (int ksub = 0; ksub < 2; ++ksub) {
#pragma unroll
            for (int nb = 0; nb < 8; ++nb) {
                short8 bf = *(const short8*)(&lB[buf][((nb * 2 + ksub) * 64 + L) * 8]);
                acc[nb] = __builtin_amdgcn_mfma_f32_16x16x32_bf16(af[ksub], bf, acc[nb], 0, 0, 0);
            }
        }

        __syncthreads();
#pragma unroll
        for (int c = 0; c < 2; ++c) {
            av[c][0] = avn[c][0];
            av[c][1] = avn[c][1];
        }
    }

    int col0 = L & 15;
    int rbase = m0 + w * 16 + (L >> 4) * 4;

    float a1c[8], a2c[8];
#pragma unroll
    for (int nb = 0; nb < 8; ++nb) {
        a1c[nb] = a_vec[nb * 16 + col0];
        a2c[nb] = a_vec[128 + nb * 16 + col0];
    }

#pragma unroll
    for (int r = 0; r < 4; ++r) {
        int row = rbase + r;
        bool ok = row < N_NODES;
        float p1 = 0.f, p2 = 0.f;
        if (ok) {
            unsigned short* orow = Whb + (size_t)row * OUT_FEAT;
#pragma unroll
            for (int nb = 0; nb < 8; ++nb) {
                float v = acc[nb][r];
                orow[nb * 16 + col0] = f2bf(v);
                p1 = fmaf(v, a1c[nb], p1);
                p2 = fmaf(v, a2c[nb], p2);
            }
        }
#pragma unroll
        for (int off = 8; off > 0; off >>= 1) {
            p1 += __shfl_xor(p1, off, 64);
            p2 += __shfl_xor(p2, off, 64);
        }
        if (ok && col0 == 0) {
            s1[row] = p1;
            s2[row] = p2;
        }
    }
}

// ---------------- K4: per-node softmax + aggregation ----------------
// One wave per node. 8 edges per iteration (two lane-group passes) with
// unroll 2 -> 4 independent Whb row-gathers in flight, covering the
// L2/L3 gather latency. Edges >= deg contribute p=0 (source lane's ex is 0).

__global__ __launch_bounds__(256) void node_kernel(const unsigned short* __restrict__ Whb,
                                                   const float* __restrict__ s1,
                                                   const float* __restrict__ s2,
                                                   const int* __restrict__ cnt,
                                                   const int* __restrict__ csr,
                                                   float* __restrict__ out) {
    int lane = threadIdx.x & 63;
    int w = threadIdx.x >> 6;
    int n = blockIdx.x * 4 + w;
    if (n >= N_NODES) return;
    int deg = cnt[n];
    size_t start = (size_t)n * PAD_DEG;
    int g = lane >> 4;
    int fo = lane & 15;

    float accv[8];
#pragma unroll
    for (int f = 0; f < 8; ++f) accv[f] = 0.f;
    float inv = 0.f;

    if (deg > 0) {
        float s1n = s1[n];
        int d0 = 0, d1 = 0;
        float ex0 = 0.f, ex1 = 0.f;
        if (lane < deg) {
            d0 = csr[start + lane];
            float ev = s1n + s2[d0];
            ev = ev >= 0.f ? ev : NEG_SLOPE * ev;
            ex0 = __expf(ev * INV_TEMP);
        }
        if (lane + 64 < deg) {
            d1 = csr[start + lane + 64];
            float ev = s1n + s2[d1];
            ev = ev >= 0.f ? ev : NEG_SLOPE * ev;
            ex1 = __expf(ev * INV_TEMP);
        }
        float denom = ex0 + ex1;
#pragma unroll
        for (int off = 32; off > 0; off >>= 1) denom += __shfl_xor(denom, off, 64);
        inv = 1.0f / denom;

#pragma unroll 2
        for (int jj = 0; jj < deg; jj += 8) {
            int e0 = jj + g;
            int e1 = jj + 4 + g;
            bool hi0 = jj >= 64;                 // wave-uniform
            bool hi1 = (jj + 4) >= 64;           // wave-uniform
            float p0 = __shfl(hi0 ? ex1 : ex0, e0 & 63, 64);
            int dd0 = __shfl(hi0 ? d1 : d0, e0 & 63, 64);
            float p1 = __shfl(hi1 ? ex1 : ex0, e1 & 63, 64);
            int dd1 = __shfl(hi1 ? d1 : d0, e1 & 63, 64);
            short8 row0 = *(const short8*)(Whb + (size_t)dd0 * OUT_FEAT + fo * 8);
            short8 row1 = *(const short8*)(Whb + (size_t)dd1 * OUT_FEAT + fo * 8);
#pragma unroll
            for (int f = 0; f < 8; ++f)
                accv[f] = fmaf(p0, bf2f((unsigned short)row0[f]), accv[f]);
#pragma unroll
            for (int f = 0; f < 8; ++f)
                accv[f] = fmaf(p1, bf2f((unsigned short)row1[f]), accv[f]);
        }
#pragma unroll
        for (int f = 0; f < 8; ++f) {
            accv[f] += __shfl_xor(accv[f], 16, 64);
            accv[f] += __shfl_xor(accv[f], 32, 64);
        }
    }

    if (g == 0) {
        float* orow = out + (size_t)n * OUT_FEAT + fo * 8;
        float4 o0, o1;
        o0.x = fmaxf(accv[0] * inv, 0.f); o0.y = fmaxf(accv[1] * inv, 0.f);
        o0.z = fmaxf(accv[2] * inv, 0.f); o0.w = fmaxf(accv[3] * inv, 0.f);
        o1.x = fmaxf(accv[4] * inv, 0.f); o1.y = fmaxf(accv[5] * inv, 0.f);
        o1.z = fmaxf(accv[6] * inv, 0.f); o1.w = fmaxf(accv[7] * inv, 0.f);
        *(float4*)(orow) = o0;
        *(float4*)(orow + 4) = o1;
    }
}

// ---------------- launch ----------------

extern "C" void kernel_launch(void* const* d_in, const int* in_sizes, int n_in,
                              void* d_out, int out_size, void* d_ws, size_t ws_size,
                              hipStream_t stream) {
    const float* h = (const float*)d_in[0];
    const float* W = (const float*)d_in[1];
    const float* a = (const float*)d_in[2];
    const int* edge = (const int*)d_in[3];
    const int* src = edge;
    const int* dst = edge + N_EDGES;
    float* out = (float*)d_out;

    char* ws = (char*)d_ws;
    size_t off = 0;
    auto alloc = [&](size_t bytes) -> void* {
        void* p = ws + off;
        off = (off + bytes + 255) & ~(size_t)255;
        return p;
    };
    unsigned short* Whb = (unsigned short*)alloc((size_t)N_NODES * OUT_FEAT * sizeof(unsigned short));
    float* s1 = (float*)alloc((size_t)N_NODES * sizeof(float));
    float* s2 = (float*)alloc((size_t)N_NODES * sizeof(float));
    int* cnt = (int*)alloc((size_t)N_NODES * sizeof(int));
    int* csr = (int*)alloc((size_t)N_NODES * PAD_DEG * sizeof(int));
    unsigned short* Wt = (unsigned short*)alloc((size_t)IN_FEAT * OUT_FEAT * sizeof(unsigned short));
    int* bucket_cursor = (int*)alloc((size_t)BUCKETS * sizeof(int));
    int* binned = (int*)alloc((size_t)BUCKETS * BCAP * sizeof(int));

    hipMemsetAsync(bucket_cursor, 0, BUCKETS * sizeof(int), stream);
    build_kernel<<<A_BLOCKS + CONV_BLOCKS, 256, 0, stream>>>(W, Wt, src, dst, bucket_cursor, binned);
    gemm_binB_kernel<<<BUCKETS + GEMM_BLOCKS, 256, 0, stream>>>(h, Wt, a, Whb, s1, s2,
                                                                bucket_cursor, binned, cnt, csr);
    node_kernel<<<(N_NODES + 3) / 4, 256, 0, stream>>>(Whb, s1, s2, cnt, csr, out);
}

// Round 7
// 266.116 us; speedup vs baseline: 1.1623x; 1.0017x over previous
//
#include <hip/hip_runtime.h>
#include <cstdint>
#include <cstddef>

#define N_NODES 50000
#define N_EDGES 1600000
#define IN_FEAT 512
#define OUT_FEAT 128
#define NEG_SLOPE 0.01f
#define INV_TEMP 2.0f
#define PAD_DEG 128     // P(Poisson(32) >= 128) ~ e^-81: never

// two-phase CSR build
#define BUCKETS 400
#define BNODES 125      // nodes per bucket (400*125 = 50000)
#define BCAP 5000       // bucket capacity; Poisson(4000) max over 400 ~ 4300
#define A_BLOCKS 500
#define A_EPC (N_EDGES / A_BLOCKS)   // 3200 edges per block
#define A_G4 (A_EPC / 4)             // 800 int4 groups

#define CONV_BLOCKS ((IN_FEAT * OUT_FEAT) / 256)   // 256
#define GEMM_BLOCKS ((N_NODES + 63) / 64)          // 782 (tile 64x128)

typedef __attribute__((ext_vector_type(8))) short short8;
typedef __attribute__((ext_vector_type(4))) float f32x4;

#define GLOBAL_AS __attribute__((address_space(1)))
#define LDS_AS __attribute__((address_space(3)))

__device__ inline unsigned short f2bf(float x) {
    unsigned int u = __float_as_uint(x);
    unsigned int r = (u + 0x7fffu + ((u >> 16) & 1u)) >> 16;
    return (unsigned short)r;
}
__device__ inline float bf2f(unsigned short b) {
    return __uint_as_float(((unsigned int)b) << 16);
}

// ---------------- K2: fused {binA, convert_w} ----------------
// Requires bucket_cursor pre-zeroed (hipMemsetAsync before this kernel).

__global__ __launch_bounds__(256) void build_kernel(const float* __restrict__ W,
                                                    unsigned short* __restrict__ Wt,
                                                    const int* __restrict__ src,
                                                    const int* __restrict__ dst,
                                                    int* __restrict__ bucket_cursor,
                                                    int* __restrict__ binned) {
    __shared__ int cntL[BUCKETS];
    __shared__ int baseL[BUCKETS];

    if (blockIdx.x >= A_BLOCKS) {
        // ---- convert_w role: W (IN_FEAT x OUT_FEAT, row-major) -> Wt bf16 [n][k]
        int tid = (blockIdx.x - A_BLOCKS) * 256 + threadIdx.x;
        if (tid < IN_FEAT * OUT_FEAT) {
            int n = tid >> 9;
            int k = tid & 511;
            Wt[tid] = f2bf(W[k * OUT_FEAT + n]);
        }
        return;
    }

    // ---- binA role
    int t = threadIdx.x;
    for (int i = t; i < BUCKETS; i += 256) cntL[i] = 0;
    __syncthreads();
    size_t ebase = (size_t)blockIdx.x * A_EPC;

    for (int g = t; g < A_G4; g += 256) {
        int4 s4 = *(const int4*)(src + ebase + (size_t)g * 4);
#pragma unroll
        for (int j = 0; j < 4; ++j) {
            int s = (&s4.x)[j];
            atomicAdd(&cntL[s / BNODES], 1);
        }
    }
    __syncthreads();
    for (int i = t; i < BUCKETS; i += 256) {
        int c = cntL[i];
        baseL[i] = c ? atomicAdd(&bucket_cursor[i], c) : 0;
        cntL[i] = 0;
    }
    __syncthreads();
    for (int g = t; g < A_G4; g += 256) {
        int4 s4 = *(const int4*)(src + ebase + (size_t)g * 4);
        int4 d4 = *(const int4*)(dst + ebase + (size_t)g * 4);
#pragma unroll
        for (int j = 0; j < 4; ++j) {
            int s = (&s4.x)[j];
            int b = s / BNODES;
            int sl = s - b * BNODES;
            int pos = atomicAdd(&cntL[b], 1);
            int slot = baseL[b] + pos;
            if (slot < BCAP)
                binned[(size_t)b * BCAP + slot] = (sl << 16) | (&d4.x)[j];
        }
    }
}

// ---------------- K3: fused {binB, mfma_gemm} ----------------
// v7 GEMM: same staging/fragment layout as the proven round-2 kernel, but
// the per-k-step full drain (__syncthreads => s_waitcnt vmcnt(0)) is
// replaced by counted s_waitcnt vmcnt(8) + raw s_barrier, with a TRIPLE-
// buffered B tile (stage distance 2 => ~2 iterations of HBM latency hidden).
// Counted-wait safety:
//  * exactly 8 VMEM ops per pipelined iteration (4 global_load_lds + 4
//    A-prefetch loads); A loads are UNCONDITIONAL via row-clamp so counts
//    are wave-uniform (boundary blocks included).
//  * vmcnt(8) = "all but the 8 newest done": cross-iteration ordering is
//    pinned by the memory-clobbered asm at each barrier, so everything
//    older — incl. the stage of the tile read next iteration — is complete.
//  * ds_read results are consumed by MFMAs (register deps force lgkm
//    drain) before the barrier, so buffer overwrite at distance 3 is safe.

__global__ __launch_bounds__(256) void gemm_binB_kernel(const float* __restrict__ h,
                                                        const unsigned short* __restrict__ Wt,
                                                        const float* __restrict__ a_vec,
                                                        unsigned short* __restrict__ Whb,
                                                        float* __restrict__ s1,
                                                        float* __restrict__ s2,
                                                        const int* __restrict__ bucket_cursor,
                                                        const int* __restrict__ binned,
                                                        int* __restrict__ cnt,
                                                        int* __restrict__ csr) {
    __shared__ unsigned short lB[3][8 * 2 * 64 * 8];   // 48 KB triple buffer

    if (blockIdx.x < BUCKETS) {
        // ---- binB role: bucket -> padded CSR
        int* cL = (int*)&lB[0][0];
        int b = blockIdx.x;
        int t = threadIdx.x;
        if (t < BNODES) cL[t] = 0;
        __syncthreads();
        int m = min(bucket_cursor[b], BCAP);
        const int* bp = binned + (size_t)b * BCAP;
        int n0 = b * BNODES;
        for (int i = t; i < m; i += 256) {
            int p = bp[i];
            int sl = p >> 16;
            int d = p & 0xFFFF;
            int pos = atomicAdd(&cL[sl], 1);
            if (pos < PAD_DEG) csr[(size_t)(n0 + sl) * PAD_DEG + pos] = d;
        }
        __syncthreads();
        if (t < BNODES) cnt[n0 + t] = min(cL[t], PAD_DEG);
        return;
    }

    // ---- gemm role: tile 64x128, 4 waves, BK=64
    int bid = blockIdx.x - BUCKETS;
    int t = threadIdx.x;
    int w = t >> 6;
    int L = t & 63;
    int m0 = bid * 64;

    int arow = m0 + w * 16 + (L & 15);
    int arow_c = arow < N_NODES ? arow : N_NODES - 1;   // clamp: loads unconditional
    int kq = (L >> 4) * 8;
    const float* arp = h + (size_t)arow_c * IN_FEAT + kq;

    f32x4 acc[8];
#pragma unroll
    for (int i = 0; i < 8; ++i) acc[i] = (f32x4){0.f, 0.f, 0.f, 0.f};

    auto stageB = [&](int slot, int k0) {
#pragma unroll
        for (int c = 0; c < 4; ++c) {
            int nb = w * 2 + (c >> 1);
            int ksub = c & 1;
            const GLOBAL_AS unsigned short* g =
                (const GLOBAL_AS unsigned short*)(Wt + (size_t)(nb * 16 + (L & 15)) * IN_FEAT +
                                                  (k0 + ksub * 32 + kq));
            LDS_AS unsigned short* lp = (LDS_AS unsigned short*)(&lB[slot][(nb * 2 + ksub) * 512]);
            __builtin_amdgcn_global_load_lds((const GLOBAL_AS void*)g, (LDS_AS void*)lp, 16, 0, 0);
        }
    };
    auto loadA = [&](int step, float4 out[4]) {
        const float* p = arp + step * 64;
        out[0] = *(const float4*)(p);
        out[1] = *(const float4*)(p + 4);
        out[2] = *(const float4*)(p + 32);
        out[3] = *(const float4*)(p + 36);
    };
    auto convA = [&](const float4 a[4], short8& f0, short8& f1) {
        short8 v;
        v[0] = (short)f2bf(a[0].x); v[1] = (short)f2bf(a[0].y);
        v[2] = (short)f2bf(a[0].z); v[3] = (short)f2bf(a[0].w);
        v[4] = (short)f2bf(a[1].x); v[5] = (short)f2bf(a[1].y);
        v[6] = (short)f2bf(a[1].z); v[7] = (short)f2bf(a[1].w);
        f0 = v;
        v[0] = (short)f2bf(a[2].x); v[1] = (short)f2bf(a[2].y);
        v[2] = (short)f2bf(a[2].z); v[3] = (short)f2bf(a[2].w);
        v[4] = (short)f2bf(a[3].x); v[5] = (short)f2bf(a[3].y);
        v[6] = (short)f2bf(a[3].z); v[7] = (short)f2bf(a[3].w);
        f1 = v;
    };

    float4 avA[4], avB[4], avC[4];
#pragma unroll
    for (int q = 0; q < 4; ++q) avC[q] = make_float4(0.f, 0.f, 0.f, 0.f);

    // prologue: stage k-steps 0,1; A for steps 0,1
    stageB(0, 0);
    asm volatile("" ::: "memory");   // pin: stage(0) oldest in vmcnt order
    stageB(1, 64);
    loadA(0, avA);
    loadA(1, avB);
    asm volatile("s_waitcnt vmcnt(12)" ::: "memory");   // stage(0) complete
    __builtin_amdgcn_s_barrier();

#pragma unroll
    for (int it = 0; it < 8; ++it) {
        if (it < 6) {
            stageB((it + 2) % 3, (it + 2) * 64);   // 4 VMEM
            loadA(it + 2, avC);                    // 4 VMEM
        }

        short8 af0, af1;
        convA(avA, af0, af1);   // compiler waits avA's loads (in-order drain
                                // => everything older, incl. this buf's stage)

        const int buf = it % 3;
#pragma unroll
        for (int nb = 0; nb < 8; ++nb) {
            short8 bf = *(const short8*)(&lB[buf][((nb * 2 + 0) * 64 + L) * 8]);
            acc[nb] = __builtin_amdgcn_mfma_f32_16x16x32_bf16(af0, bf, acc[nb], 0, 0, 0);
        }
#pragma unroll
        for (int nb = 0; nb < 8; ++nb) {
            short8 bf = *(const short8*)(&lB[buf][((nb * 2 + 1) * 64 + L) * 8]);
            acc[nb] = __builtin_amdgcn_mfma_f32_16x16x32_bf16(af1, bf, acc[nb], 0, 0, 0);
        }

#pragma unroll
        for (int q = 0; q < 4; ++q) { avA[q] = avB[q]; avB[q] = avC[q]; }

        if (it < 6) {
            // keep this iteration's 8 loads in flight across the barrier;
            // everything older (next tile's stage) is complete.
            asm volatile("s_waitcnt vmcnt(8)" ::: "memory");
            __builtin_amdgcn_s_barrier();
        } else if (it == 6) {
            asm volatile("s_waitcnt vmcnt(0)" ::: "memory");
            __builtin_amdgcn_s_barrier();
        }
        // it == 7: last tile, no barrier needed
    }

    int col0 = L & 15;
    int rbase = m0 + w * 16 + (L >> 4) * 4;

    float a1c[8], a2c[8];
#pragma unroll
    for (int nb = 0; nb < 8; ++nb) {
        a1c[nb] = a_vec[nb * 16 + col0];
        a2c[nb] = a_vec[128 + nb * 16 + col0];
    }

#pragma unroll
    for (int r = 0; r < 4; ++r) {
        int row = rbase + r;
        bool ok = row < N_NODES;
        float p1 = 0.f, p2 = 0.f;
        if (ok) {
            unsigned short* orow = Whb + (size_t)row * OUT_FEAT;
#pragma unroll
            for (int nb = 0; nb < 8; ++nb) {
                float v = acc[nb][r];
                orow[nb * 16 + col0] = f2bf(v);
                p1 = fmaf(v, a1c[nb], p1);
                p2 = fmaf(v, a2c[nb], p2);
            }
        }
#pragma unroll
        for (int off = 8; off > 0; off >>= 1) {
            p1 += __shfl_xor(p1, off, 64);
            p2 += __shfl_xor(p2, off, 64);
        }
        if (ok && col0 == 0) {
            s1[row] = p1;
            s2[row] = p2;
        }
    }
}

// ---------------- K4: per-node softmax + aggregation ----------------

__global__ __launch_bounds__(256) void node_kernel(const unsigned short* __restrict__ Whb,
                                                   const float* __restrict__ s1,
                                                   const float* __restrict__ s2,
                                                   const int* __restrict__ cnt,
                                                   const int* __restrict__ csr,
                                                   float* __restrict__ out) {
    int lane = threadIdx.x & 63;
    int w = threadIdx.x >> 6;
    int n = blockIdx.x * 4 + w;
    if (n >= N_NODES) return;
    int deg = cnt[n];
    size_t start = (size_t)n * PAD_DEG;
    int g = lane >> 4;
    int fo = lane & 15;

    float accv[8];
#pragma unroll
    for (int f = 0; f < 8; ++f) accv[f] = 0.f;
    float inv = 0.f;

    if (deg > 0) {
        float s1n = s1[n];
        int d0 = 0, d1 = 0;
        float ex0 = 0.f, ex1 = 0.f;
        if (lane < deg) {
            d0 = csr[start + lane];
            float ev = s1n + s2[d0];
            ev = ev >= 0.f ? ev : NEG_SLOPE * ev;
            ex0 = __expf(ev * INV_TEMP);
        }
        if (lane + 64 < deg) {
            d1 = csr[start + lane + 64];
            float ev = s1n + s2[d1];
            ev = ev >= 0.f ? ev : NEG_SLOPE * ev;
            ex1 = __expf(ev * INV_TEMP);
        }
        float denom = ex0 + ex1;
#pragma unroll
        for (int off = 32; off > 0; off >>= 1) denom += __shfl_xor(denom, off, 64);
        inv = 1.0f / denom;

#pragma unroll 2
        for (int jj = 0; jj < deg; jj += 8) {
            int e0 = jj + g;
            int e1 = jj + 4 + g;
            bool hi0 = jj >= 64;                 // wave-uniform
            bool hi1 = (jj + 4) >= 64;           // wave-uniform
            float p0 = __shfl(hi0 ? ex1 : ex0, e0 & 63, 64);
            int dd0 = __shfl(hi0 ? d1 : d0, e0 & 63, 64);
            float p1 = __shfl(hi1 ? ex1 : ex0, e1 & 63, 64);
            int dd1 = __shfl(hi1 ? d1 : d0, e1 & 63, 64);
            short8 row0 = *(const short8*)(Whb + (size_t)dd0 * OUT_FEAT + fo * 8);
            short8 row1 = *(const short8*)(Whb + (size_t)dd1 * OUT_FEAT + fo * 8);
#pragma unroll
            for (int f = 0; f < 8; ++f)
                accv[f] = fmaf(p0, bf2f((unsigned short)row0[f]), accv[f]);
#pragma unroll
            for (int f = 0; f < 8; ++f)
                accv[f] = fmaf(p1, bf2f((unsigned short)row1[f]), accv[f]);
        }
#pragma unroll
        for (int f = 0; f < 8; ++f) {
            accv[f] += __shfl_xor(accv[f], 16, 64);
            accv[f] += __shfl_xor(accv[f], 32, 64);
        }
    }

    if (g == 0) {
        float* orow = out + (size_t)n * OUT_FEAT + fo * 8;
        float4 o0, o1;
        o0.x = fmaxf(accv[0] * inv, 0.f); o0.y = fmaxf(accv[1] * inv, 0.f);
        o0.z = fmaxf(accv[2] * inv, 0.f); o0.w = fmaxf(accv[3] * inv, 0.f);
        o1.x = fmaxf(accv[4] * inv, 0.f); o1.y = fmaxf(accv[5] * inv, 0.f);
        o1.z = fmaxf(accv[6] * inv, 0.f); o1.w = fmaxf(accv[7] * inv, 0.f);
        *(float4*)(orow) = o0;
        *(float4*)(orow + 4) = o1;
    }
}

// ---------------- launch ----------------

extern "C" void kernel_launch(void* const* d_in, const int* in_sizes, int n_in,
                              void* d_out, int out_size, void* d_ws, size_t ws_size,
                              hipStream_t stream) {
    const float* h = (const float*)d_in[0];
    const float* W = (const float*)d_in[1];
    const float* a = (const float*)d_in[2];
    const int* edge = (const int*)d_in[3];
    const int* src = edge;
    const int* dst = edge + N_EDGES;
    float* out = (float*)d_out;

    char* ws = (char*)d_ws;
    size_t off = 0;
    auto alloc = [&](size_t bytes) -> void* {
        void* p = ws + off;
        off = (off + bytes + 255) & ~(size_t)255;
        return p;
    };
    unsigned short* Whb = (unsigned short*)alloc((size_t)N_NODES * OUT_FEAT * sizeof(unsigned short));
    float* s1 = (float*)alloc((size_t)N_NODES * sizeof(float));
    float* s2 = (float*)alloc((size_t)N_NODES * sizeof(float));
    int* cnt = (int*)alloc((size_t)N_NODES * sizeof(int));
    int* csr = (int*)alloc((size_t)N_NODES * PAD_DEG * sizeof(int));
    unsigned short* Wt = (unsigned short*)alloc((size_t)IN_FEAT * OUT_FEAT * sizeof(unsigned short));
    int* bucket_cursor = (int*)alloc((size_t)BUCKETS * sizeof(int));
    int* binned = (int*)alloc((size_t)BUCKETS * BCAP * sizeof(int));

    hipMemsetAsync(bucket_cursor, 0, BUCKETS * sizeof(int), stream);
    build_kernel<<<A_BLOCKS + CONV_BLOCKS, 256, 0, stream>>>(W, Wt, src, dst, bucket_cursor, binned);
    gemm_binB_kernel<<<BUCKETS + GEMM_BLOCKS, 256, 0, stream>>>(h, Wt, a, Whb, s1, s2,
                                                                bucket_cursor, binned, cnt, csr);
    node_kernel<<<(N_NODES + 3) / 4, 256, 0, stream>>>(Whb, s1, s2, cnt, csr, out);
}

// Round 8
// 259.078 us; speedup vs baseline: 1.1939x; 1.0272x over previous
//
#include <hip/hip_runtime.h>
#include <cstdint>
#include <cstddef>

#define N_NODES 50000
#define N_EDGES 1600000
#define IN_FEAT 512
#define OUT_FEAT 128
#define NEG_SLOPE 0.01f
#define INV_TEMP 2.0f
#define PAD_DEG 128     // P(Poisson(32) >= 128) ~ e^-81: never

// two-phase CSR build
#define BUCKETS 400
#define BNODES 125      // nodes per bucket (400*125 = 50000)
#define BCAP 5000       // bucket capacity; Poisson(4000) max over 400 ~ 4300
#define A_BLOCKS 500
#define A_EPC (N_EDGES / A_BLOCKS)   // 3200 edges per block
#define A_G4 (A_EPC / 4)             // 800 int4 groups

#define CONV_BLOCKS ((IN_FEAT * OUT_FEAT) / 256)   // 256
#define GEMM_BLOCKS ((N_NODES + 127) / 128)        // 391 (tile 128x128, 8 waves)

typedef __attribute__((ext_vector_type(8))) short short8;
typedef __attribute__((ext_vector_type(4))) float f32x4;

#define GLOBAL_AS __attribute__((address_space(1)))
#define LDS_AS __attribute__((address_space(3)))

__device__ inline unsigned short f2bf(float x) {
    unsigned int u = __float_as_uint(x);
    unsigned int r = (u + 0x7fffu + ((u >> 16) & 1u)) >> 16;
    return (unsigned short)r;
}
__device__ inline float bf2f(unsigned short b) {
    return __uint_as_float(((unsigned int)b) << 16);
}

// ---------------- K2: fused {binA, convert_w} ----------------
// Requires bucket_cursor pre-zeroed (hipMemsetAsync before this kernel).

__global__ __launch_bounds__(256) void build_kernel(const float* __restrict__ W,
                                                    unsigned short* __restrict__ Wt,
                                                    const int* __restrict__ src,
                                                    const int* __restrict__ dst,
                                                    int* __restrict__ bucket_cursor,
                                                    int* __restrict__ binned) {
    __shared__ int cntL[BUCKETS];
    __shared__ int baseL[BUCKETS];

    if (blockIdx.x >= A_BLOCKS) {
        // ---- convert_w role: W (IN_FEAT x OUT_FEAT, row-major) -> Wt bf16 [n][k]
        int tid = (blockIdx.x - A_BLOCKS) * 256 + threadIdx.x;
        if (tid < IN_FEAT * OUT_FEAT) {
            int n = tid >> 9;
            int k = tid & 511;
            Wt[tid] = f2bf(W[k * OUT_FEAT + n]);
        }
        return;
    }

    // ---- binA role
    int t = threadIdx.x;
    for (int i = t; i < BUCKETS; i += 256) cntL[i] = 0;
    __syncthreads();
    size_t ebase = (size_t)blockIdx.x * A_EPC;

    for (int g = t; g < A_G4; g += 256) {
        int4 s4 = *(const int4*)(src + ebase + (size_t)g * 4);
#pragma unroll
        for (int j = 0; j < 4; ++j) {
            int s = (&s4.x)[j];
            atomicAdd(&cntL[s / BNODES], 1);
        }
    }
    __syncthreads();
    for (int i = t; i < BUCKETS; i += 256) {
        int c = cntL[i];
        baseL[i] = c ? atomicAdd(&bucket_cursor[i], c) : 0;
        cntL[i] = 0;
    }
    __syncthreads();
    for (int g = t; g < A_G4; g += 256) {
        int4 s4 = *(const int4*)(src + ebase + (size_t)g * 4);
        int4 d4 = *(const int4*)(dst + ebase + (size_t)g * 4);
#pragma unroll
        for (int j = 0; j < 4; ++j) {
            int s = (&s4.x)[j];
            int b = s / BNODES;
            int sl = s - b * BNODES;
            int pos = atomicAdd(&cntL[b], 1);
            int slot = baseL[b] + pos;
            if (slot < BCAP)
                binned[(size_t)b * BCAP + slot] = (sl << 16) | (&d4.x)[j];
        }
    }
}

// ---------------- K3: fused {binB, mfma_gemm} ----------------
// v8 GEMM: 8-wave / 512-thread blocks, tile 128x128. Per-wave structure is
// identical to the proven 4-wave kernel (16 rows/wave, acc[8], same LDS slot
// layout), but: staging per wave HALVES (2 global_load_lds calls vs 4 — the
// 16KB B stage is shared by 8 waves), Wt re-reads halve (391 blocks), and
// the 48KB triple buffer now serves 8 waves -> LDS cap = 3 blocks x 8 waves
// = 24 waves/CU (was ~12). Counted vmcnt schedule from round 7, recomputed
// for 6 VMEM/thread/step (2 stage + 4 A, unconditional via row clamp).

__global__ __launch_bounds__(512) void gemm_binB_kernel(const float* __restrict__ h,
                                                        const unsigned short* __restrict__ Wt,
                                                        const float* __restrict__ a_vec,
                                                        unsigned short* __restrict__ Whb,
                                                        float* __restrict__ s1,
                                                        float* __restrict__ s2,
                                                        const int* __restrict__ bucket_cursor,
                                                        const int* __restrict__ binned,
                                                        int* __restrict__ cnt,
                                                        int* __restrict__ csr) {
    __shared__ unsigned short lB[3][8 * 2 * 64 * 8];   // 48 KB triple buffer

    if (blockIdx.x < BUCKETS) {
        // ---- binB role: bucket -> padded CSR (512-thread stride)
        int* cL = (int*)&lB[0][0];
        int b = blockIdx.x;
        int t = threadIdx.x;
        if (t < BNODES) cL[t] = 0;
        __syncthreads();
        int m = min(bucket_cursor[b], BCAP);
        const int* bp = binned + (size_t)b * BCAP;
        int n0 = b * BNODES;
        for (int i = t; i < m; i += 512) {
            int p = bp[i];
            int sl = p >> 16;
            int d = p & 0xFFFF;
            int pos = atomicAdd(&cL[sl], 1);
            if (pos < PAD_DEG) csr[(size_t)(n0 + sl) * PAD_DEG + pos] = d;
        }
        __syncthreads();
        if (t < BNODES) cnt[n0 + t] = min(cL[t], PAD_DEG);
        return;
    }

    // ---- gemm role: tile 128x128, 8 waves (16 rows each), BK=64
    int bid = blockIdx.x - BUCKETS;
    int t = threadIdx.x;
    int w = t >> 6;          // 0..7
    int L = t & 63;
    int m0 = bid * 128;

    int arow = m0 + w * 16 + (L & 15);
    int arow_c = arow < N_NODES ? arow : N_NODES - 1;   // clamp: loads unconditional
    int kq = (L >> 4) * 8;
    const float* arp = h + (size_t)arow_c * IN_FEAT + kq;

    f32x4 acc[8];
#pragma unroll
    for (int i = 0; i < 8; ++i) acc[i] = (f32x4){0.f, 0.f, 0.f, 0.f};

    // wave w stages slots (nb=w, ksub=0,1): 2 global_load_lds per thread.
    auto stageB = [&](int slot, int k0) {
#pragma unroll
        for (int ksub = 0; ksub < 2; ++ksub) {
            const GLOBAL_AS unsigned short* g =
                (const GLOBAL_AS unsigned short*)(Wt + (size_t)(w * 16 + (L & 15)) * IN_FEAT +
                                                  (k0 + ksub * 32 + kq));
            LDS_AS unsigned short* lp = (LDS_AS unsigned short*)(&lB[slot][(w * 2 + ksub) * 512]);
            __builtin_amdgcn_global_load_lds((const GLOBAL_AS void*)g, (LDS_AS void*)lp, 16, 0, 0);
        }
    };
    auto loadA = [&](int step, float4 out[4]) {
        const float* p = arp + step * 64;
        out[0] = *(const float4*)(p);
        out[1] = *(const float4*)(p + 4);
        out[2] = *(const float4*)(p + 32);
        out[3] = *(const float4*)(p + 36);
    };
    auto convA = [&](const float4 a[4], short8& f0, short8& f1) {
        short8 v;
        v[0] = (short)f2bf(a[0].x); v[1] = (short)f2bf(a[0].y);
        v[2] = (short)f2bf(a[0].z); v[3] = (short)f2bf(a[0].w);
        v[4] = (short)f2bf(a[1].x); v[5] = (short)f2bf(a[1].y);
        v[6] = (short)f2bf(a[1].z); v[7] = (short)f2bf(a[1].w);
        f0 = v;
        v[0] = (short)f2bf(a[2].x); v[1] = (short)f2bf(a[2].y);
        v[2] = (short)f2bf(a[2].z); v[3] = (short)f2bf(a[2].w);
        v[4] = (short)f2bf(a[3].x); v[5] = (short)f2bf(a[3].y);
        v[6] = (short)f2bf(a[3].z); v[7] = (short)f2bf(a[3].w);
        f1 = v;
    };

    float4 avA[4], avB[4], avC[4];
#pragma unroll
    for (int q = 0; q < 4; ++q) avC[q] = make_float4(0.f, 0.f, 0.f, 0.f);

    // prologue: stage k-steps 0,1; A for steps 0,1. VMEM order (oldest first):
    // stage0(2), stage1(2), A0(4), A1(4) => stage0 complete at vmcnt(10).
    stageB(0, 0);
    asm volatile("" ::: "memory");   // pin: stage(0) oldest in vmcnt order
    stageB(1, 64);
    loadA(0, avA);
    loadA(1, avB);
    asm volatile("s_waitcnt vmcnt(10)" ::: "memory");
    __builtin_amdgcn_s_barrier();

#pragma unroll
    for (int it = 0; it < 8; ++it) {
        if (it < 6) {
            stageB((it + 2) % 3, (it + 2) * 64);   // 2 VMEM
            loadA(it + 2, avC);                    // 4 VMEM
        }

        short8 af0, af1;
        convA(avA, af0, af1);   // register deps force avA's loads complete

        const int buf = it % 3;
#pragma unroll
        for (int nb = 0; nb < 8; ++nb) {
            short8 bf = *(const short8*)(&lB[buf][((nb * 2 + 0) * 64 + L) * 8]);
            acc[nb] = __builtin_amdgcn_mfma_f32_16x16x32_bf16(af0, bf, acc[nb], 0, 0, 0);
        }
#pragma unroll
        for (int nb = 0; nb < 8; ++nb) {
            short8 bf = *(const short8*)(&lB[buf][((nb * 2 + 1) * 64 + L) * 8]);
            acc[nb] = __builtin_amdgcn_mfma_f32_16x16x32_bf16(af1, bf, acc[nb], 0, 0, 0);
        }

#pragma unroll
        for (int q = 0; q < 4; ++q) { avA[q] = avB[q]; avB[q] = avC[q]; }

        if (it < 6) {
            // keep this iteration's 6 VMEM (2 stage + 4 A) in flight across
            // the barrier; everything older (next tile's stage) is complete.
            asm volatile("s_waitcnt vmcnt(6)" ::: "memory");
            __builtin_amdgcn_s_barrier();
        } else if (it == 6) {
            asm volatile("s_waitcnt vmcnt(0)" ::: "memory");
            __builtin_amdgcn_s_barrier();
        }
        // it == 7: last tile, no barrier needed
    }

    int col0 = L & 15;
    int rbase = m0 + w * 16 + (L >> 4) * 4;

    float a1c[8], a2c[8];
#pragma unroll
    for (int nb = 0; nb < 8; ++nb) {
        a1c[nb] = a_vec[nb * 16 + col0];
        a2c[nb] = a_vec[128 + nb * 16 + col0];
    }

#pragma unroll
    for (int r = 0; r < 4; ++r) {
        int row = rbase + r;
        bool ok = row < N_NODES;
        float p1 = 0.f, p2 = 0.f;
        if (ok) {
            unsigned short* orow = Whb + (size_t)row * OUT_FEAT;
#pragma unroll
            for (int nb = 0; nb < 8; ++nb) {
                float v = acc[nb][r];
                orow[nb * 16 + col0] = f2bf(v);
                p1 = fmaf(v, a1c[nb], p1);
                p2 = fmaf(v, a2c[nb], p2);
            }
        }
#pragma unroll
        for (int off = 8; off > 0; off >>= 1) {
            p1 += __shfl_xor(p1, off, 64);
            p2 += __shfl_xor(p2, off, 64);
        }
        if (ok && col0 == 0) {
            s1[row] = p1;
            s2[row] = p2;
        }
    }
}

// ---------------- K4: per-node softmax + aggregation ----------------

__global__ __launch_bounds__(256) void node_kernel(const unsigned short* __restrict__ Whb,
                                                   const float* __restrict__ s1,
                                                   const float* __restrict__ s2,
                                                   const int* __restrict__ cnt,
                                                   const int* __restrict__ csr,
                                                   float* __restrict__ out) {
    int lane = threadIdx.x & 63;
    int w = threadIdx.x >> 6;
    int n = blockIdx.x * 4 + w;
    if (n >= N_NODES) return;
    int deg = cnt[n];
    size_t start = (size_t)n * PAD_DEG;
    int g = lane >> 4;
    int fo = lane & 15;

    float accv[8];
#pragma unroll
    for (int f = 0; f < 8; ++f) accv[f] = 0.f;
    float inv = 0.f;

    if (deg > 0) {
        float s1n = s1[n];
        int d0 = 0, d1 = 0;
        float ex0 = 0.f, ex1 = 0.f;
        if (lane < deg) {
            d0 = csr[start + lane];
            float ev = s1n + s2[d0];
            ev = ev >= 0.f ? ev : NEG_SLOPE * ev;
            ex0 = __expf(ev * INV_TEMP);
        }
        if (lane + 64 < deg) {
            d1 = csr[start + lane + 64];
            float ev = s1n + s2[d1];
            ev = ev >= 0.f ? ev : NEG_SLOPE * ev;
            ex1 = __expf(ev * INV_TEMP);
        }
        float denom = ex0 + ex1;
#pragma unroll
        for (int off = 32; off > 0; off >>= 1) denom += __shfl_xor(denom, off, 64);
        inv = 1.0f / denom;

#pragma unroll 2
        for (int jj = 0; jj < deg; jj += 8) {
            int e0 = jj + g;
            int e1 = jj + 4 + g;
            bool hi0 = jj >= 64;                 // wave-uniform
            bool hi1 = (jj + 4) >= 64;           // wave-uniform
            float p0 = __shfl(hi0 ? ex1 : ex0, e0 & 63, 64);
            int dd0 = __shfl(hi0 ? d1 : d0, e0 & 63, 64);
            float p1 = __shfl(hi1 ? ex1 : ex0, e1 & 63, 64);
            int dd1 = __shfl(hi1 ? d1 : d0, e1 & 63, 64);
            short8 row0 = *(const short8*)(Whb + (size_t)dd0 * OUT_FEAT + fo * 8);
            short8 row1 = *(const short8*)(Whb + (size_t)dd1 * OUT_FEAT + fo * 8);
#pragma unroll
            for (int f = 0; f < 8; ++f)
                accv[f] = fmaf(p0, bf2f((unsigned short)row0[f]), accv[f]);
#pragma unroll
            for (int f = 0; f < 8; ++f)
                accv[f] = fmaf(p1, bf2f((unsigned short)row1[f]), accv[f]);
        }
#pragma unroll
        for (int f = 0; f < 8; ++f) {
            accv[f] += __shfl_xor(accv[f], 16, 64);
            accv[f] += __shfl_xor(accv[f], 32, 64);
        }
    }

    if (g == 0) {
        float* orow = out + (size_t)n * OUT_FEAT + fo * 8;
        float4 o0, o1;
        o0.x = fmaxf(accv[0] * inv, 0.f); o0.y = fmaxf(accv[1] * inv, 0.f);
        o0.z = fmaxf(accv[2] * inv, 0.f); o0.w = fmaxf(accv[3] * inv, 0.f);
        o1.x = fmaxf(accv[4] * inv, 0.f); o1.y = fmaxf(accv[5] * inv, 0.f);
        o1.z = fmaxf(accv[6] * inv, 0.f); o1.w = fmaxf(accv[7] * inv, 0.f);
        *(float4*)(orow) = o0;
        *(float4*)(orow + 4) = o1;
    }
}

// ---------------- launch ----------------

extern "C" void kernel_launch(void* const* d_in, const int* in_sizes, int n_in,
                              void* d_out, int out_size, void* d_ws, size_t ws_size,
                              hipStream_t stream) {
    const float* h = (const float*)d_in[0];
    const float* W = (const float*)d_in[1];
    const float* a = (const float*)d_in[2];
    const int* edge = (const int*)d_in[3];
    const int* src = edge;
    const int* dst = edge + N_EDGES;
    float* out = (float*)d_out;

    char* ws = (char*)d_ws;
    size_t off = 0;
    auto alloc = [&](size_t bytes) -> void* {
        void* p = ws + off;
        off = (off + bytes + 255) & ~(size_t)255;
        return p;
    };
    unsigned short* Whb = (unsigned short*)alloc((size_t)N_NODES * OUT_FEAT * sizeof(unsigned short));
    float* s1 = (float*)alloc((size_t)N_NODES * sizeof(float));
    float* s2 = (float*)alloc((size_t)N_NODES * sizeof(float));
    int* cnt = (int*)alloc((size_t)N_NODES * sizeof(int));
    int* csr = (int*)alloc((size_t)N_NODES * PAD_DEG * sizeof(int));
    unsigned short* Wt = (unsigned short*)alloc((size_t)IN_FEAT * OUT_FEAT * sizeof(unsigned short));
    int* bucket_cursor = (int*)alloc((size_t)BUCKETS * sizeof(int));
    int* binned = (int*)alloc((size_t)BUCKETS * BCAP * sizeof(int));

    hipMemsetAsync(bucket_cursor, 0, BUCKETS * sizeof(int), stream);
    build_kernel<<<A_BLOCKS + CONV_BLOCKS, 256, 0, stream>>>(W, Wt, src, dst, bucket_cursor, binned);
    gemm_binB_kernel<<<BUCKETS + GEMM_BLOCKS, 512, 0, stream>>>(h, Wt, a, Whb, s1, s2,
                                                                bucket_cursor, binned, cnt, csr);
    node_kernel<<<(N_NODES + 3) / 4, 256, 0, stream>>>(Whb, s1, s2, cnt, csr, out);
}

// Round 9
// 244.578 us; speedup vs baseline: 1.2647x; 1.0593x over previous
//
#include <hip/hip_runtime.h>
#include <cstdint>
#include <cstddef>

#define N_NODES 50000
#define N_EDGES 1600000
#define IN_FEAT 512
#define OUT_FEAT 128
#define NEG_SLOPE 0.01f
#define INV_TEMP 2.0f
#define PAD_DEG 128     // P(Poisson(32) >= 128) ~ e^-81: never

// two-phase CSR build
#define BUCKETS 400
#define BNODES 125      // nodes per bucket (400*125 = 50000)
#define BCAP 5000       // bucket capacity; Poisson(4000) max over 400 ~ 4300
#define A_BLOCKS 500
#define A_EPC (N_EDGES / A_BLOCKS)   // 3200 edges per block
#define A_G4 (A_EPC / 4)             // 800 int4 groups

#define CONV_BLOCKS ((IN_FEAT * OUT_FEAT) / 256)   // 256
#define GEMM_BLOCKS ((N_NODES + 127) / 128)        // 391 (tile 128x128, 8 waves)

typedef __attribute__((ext_vector_type(8))) short short8;
typedef __attribute__((ext_vector_type(4))) float f32x4;

#define GLOBAL_AS __attribute__((address_space(1)))
#define LDS_AS __attribute__((address_space(3)))

__device__ inline unsigned short f2bf(float x) {
    unsigned int u = __float_as_uint(x);
    unsigned int r = (u + 0x7fffu + ((u >> 16) & 1u)) >> 16;
    return (unsigned short)r;
}
__device__ inline float bf2f(unsigned short b) {
    return __uint_as_float(((unsigned int)b) << 16);
}

// ---------------- K1: convert_w + zero bucket cursors ----------------
// Tiny (~5us). Runs BEFORE the fused {gemm, binA} kernel: gemm only needs
// Wt, so binA's ~50us no longer serializes ahead of the GEMM. Also absorbs
// the cursor memset (separate dispatch removed).

__global__ __launch_bounds__(256) void convw_kernel(const float* __restrict__ W,
                                                    unsigned short* __restrict__ Wt,
                                                    int* __restrict__ bucket_cursor) {
    int tid = blockIdx.x * 256 + threadIdx.x;
    if (tid < BUCKETS) bucket_cursor[tid] = 0;
    if (tid < IN_FEAT * OUT_FEAT) {
        int n = tid >> 9;
        int k = tid & 511;
        Wt[tid] = f2bf(W[k * OUT_FEAT + n]);
    }
}

// ---------------- K2: fused {mfma_gemm, binA} ----------------
// The two roles are DATA-INDEPENDENT (gemm: h,Wt -> Whb,s1,s2; binA:
// edges -> binned). Fusing makes the dispatch ~max(gemm, binA) instead of
// their serial sum: binA's atomic/latency-bound work fills the gemm's
// memory-stall bubbles. gemm blocks first (0..390, latency-critical
// pipeline starts immediately); binA blocks after (391..890).
// gemm role: v8 structure unchanged (8 waves, tile 128x128, triple-buffered
// B via global_load_lds, counted vmcnt(6) + raw s_barrier).

__global__ __launch_bounds__(512) void gemm_binA_kernel(const float* __restrict__ h,
                                                        const unsigned short* __restrict__ Wt,
                                                        const float* __restrict__ a_vec,
                                                        unsigned short* __restrict__ Whb,
                                                        float* __restrict__ s1,
                                                        float* __restrict__ s2,
                                                        const int* __restrict__ src,
                                                        const int* __restrict__ dst,
                                                        int* __restrict__ bucket_cursor,
                                                        int* __restrict__ binned) {
    __shared__ unsigned short lB[3][8 * 2 * 64 * 8];   // 48 KB (gemm); binA aliases front 3.2KB

    if (blockIdx.x >= GEMM_BLOCKS) {
        // ---- binA role: bin edges by bucket (512-thread strides)
        int* cntL = (int*)&lB[0][0];
        int* baseL = cntL + BUCKETS;
        int t = threadIdx.x;
        for (int i = t; i < BUCKETS; i += 512) cntL[i] = 0;
        __syncthreads();
        size_t ebase = (size_t)(blockIdx.x - GEMM_BLOCKS) * A_EPC;

        // pass 1: count per bucket (LDS atomics)
        for (int g = t; g < A_G4; g += 512) {
            int4 s4 = *(const int4*)(src + ebase + (size_t)g * 4);
#pragma unroll
            for (int j = 0; j < 4; ++j) {
                int s = (&s4.x)[j];
                atomicAdd(&cntL[s / BNODES], 1);
            }
        }
        __syncthreads();
        // reserve global ranges: one device atomic per (block, non-empty bucket)
        for (int i = t; i < BUCKETS; i += 512) {
            int c = cntL[i];
            baseL[i] = c ? atomicAdd(&bucket_cursor[i], c) : 0;
            cntL[i] = 0;
        }
        __syncthreads();
        // pass 2: write packed (src_local<<16)|dst into reserved slots
        for (int g = t; g < A_G4; g += 512) {
            int4 s4 = *(const int4*)(src + ebase + (size_t)g * 4);
            int4 d4 = *(const int4*)(dst + ebase + (size_t)g * 4);
#pragma unroll
            for (int j = 0; j < 4; ++j) {
                int s = (&s4.x)[j];
                int b = s / BNODES;
                int sl = s - b * BNODES;
                int pos = atomicAdd(&cntL[b], 1);
                int slot = baseL[b] + pos;
                if (slot < BCAP)
                    binned[(size_t)b * BCAP + slot] = (sl << 16) | (&d4.x)[j];
            }
        }
        return;
    }

    // ---- gemm role: tile 128x128, 8 waves (16 rows each), BK=64
    int bid = blockIdx.x;
    int t = threadIdx.x;
    int w = t >> 6;          // 0..7
    int L = t & 63;
    int m0 = bid * 128;

    int arow = m0 + w * 16 + (L & 15);
    int arow_c = arow < N_NODES ? arow : N_NODES - 1;   // clamp: loads unconditional
    int kq = (L >> 4) * 8;
    const float* arp = h + (size_t)arow_c * IN_FEAT + kq;

    f32x4 acc[8];
#pragma unroll
    for (int i = 0; i < 8; ++i) acc[i] = (f32x4){0.f, 0.f, 0.f, 0.f};

    // wave w stages slots (nb=w, ksub=0,1): 2 global_load_lds per thread.
    auto stageB = [&](int slot, int k0) {
#pragma unroll
        for (int ksub = 0; ksub < 2; ++ksub) {
            const GLOBAL_AS unsigned short* g =
                (const GLOBAL_AS unsigned short*)(Wt + (size_t)(w * 16 + (L & 15)) * IN_FEAT +
                                                  (k0 + ksub * 32 + kq));
            LDS_AS unsigned short* lp = (LDS_AS unsigned short*)(&lB[slot][(w * 2 + ksub) * 512]);
            __builtin_amdgcn_global_load_lds((const GLOBAL_AS void*)g, (LDS_AS void*)lp, 16, 0, 0);
        }
    };
    auto loadA = [&](int step, float4 out[4]) {
        const float* p = arp + step * 64;
        out[0] = *(const float4*)(p);
        out[1] = *(const float4*)(p + 4);
        out[2] = *(const float4*)(p + 32);
        out[3] = *(const float4*)(p + 36);
    };
    auto convA = [&](const float4 a[4], short8& f0, short8& f1) {
        short8 v;
        v[0] = (short)f2bf(a[0].x); v[1] = (short)f2bf(a[0].y);
        v[2] = (short)f2bf(a[0].z); v[3] = (short)f2bf(a[0].w);
        v[4] = (short)f2bf(a[1].x); v[5] = (short)f2bf(a[1].y);
        v[6] = (short)f2bf(a[1].z); v[7] = (short)f2bf(a[1].w);
        f0 = v;
        v[0] = (short)f2bf(a[2].x); v[1] = (short)f2bf(a[2].y);
        v[2] = (short)f2bf(a[2].z); v[3] = (short)f2bf(a[2].w);
        v[4] = (short)f2bf(a[3].x); v[5] = (short)f2bf(a[3].y);
        v[6] = (short)f2bf(a[3].z); v[7] = (short)f2bf(a[3].w);
        f1 = v;
    };

    float4 avA[4], avB[4], avC[4];
#pragma unroll
    for (int q = 0; q < 4; ++q) avC[q] = make_float4(0.f, 0.f, 0.f, 0.f);

    // prologue: stage k-steps 0,1; A for steps 0,1. VMEM order (oldest first):
    // stage0(2), stage1(2), A0(4), A1(4) => stage0 complete at vmcnt(10).
    stageB(0, 0);
    asm volatile("" ::: "memory");   // pin: stage(0) oldest in vmcnt order
    stageB(1, 64);
    loadA(0, avA);
    loadA(1, avB);
    asm volatile("s_waitcnt vmcnt(10)" ::: "memory");
    __builtin_amdgcn_s_barrier();

#pragma unroll
    for (int it = 0; it < 8; ++it) {
        if (it < 6) {
            stageB((it + 2) % 3, (it + 2) * 64);   // 2 VMEM
            loadA(it + 2, avC);                    // 4 VMEM
        }

        short8 af0, af1;
        convA(avA, af0, af1);   // register deps force avA's loads complete

        const int buf = it % 3;
#pragma unroll
        for (int nb = 0; nb < 8; ++nb) {
            short8 bf = *(const short8*)(&lB[buf][((nb * 2 + 0) * 64 + L) * 8]);
            acc[nb] = __builtin_amdgcn_mfma_f32_16x16x32_bf16(af0, bf, acc[nb], 0, 0, 0);
        }
#pragma unroll
        for (int nb = 0; nb < 8; ++nb) {
            short8 bf = *(const short8*)(&lB[buf][((nb * 2 + 1) * 64 + L) * 8]);
            acc[nb] = __builtin_amdgcn_mfma_f32_16x16x32_bf16(af1, bf, acc[nb], 0, 0, 0);
        }

#pragma unroll
        for (int q = 0; q < 4; ++q) { avA[q] = avB[q]; avB[q] = avC[q]; }

        if (it < 6) {
            // keep this iteration's 6 VMEM (2 stage + 4 A) in flight across
            // the barrier; everything older (next tile's stage) is complete.
            asm volatile("s_waitcnt vmcnt(6)" ::: "memory");
            __builtin_amdgcn_s_barrier();
        } else if (it == 6) {
            asm volatile("s_waitcnt vmcnt(0)" ::: "memory");
            __builtin_amdgcn_s_barrier();
        }
        // it == 7: last tile, no barrier needed
    }

    int col0 = L & 15;
    int rbase = m0 + w * 16 + (L >> 4) * 4;

    float a1c[8], a2c[8];
#pragma unroll
    for (int nb = 0; nb < 8; ++nb) {
        a1c[nb] = a_vec[nb * 16 + col0];
        a2c[nb] = a_vec[128 + nb * 16 + col0];
    }

#pragma unroll
    for (int r = 0; r < 4; ++r) {
        int row = rbase + r;
        bool ok = row < N_NODES;
        float p1 = 0.f, p2 = 0.f;
        if (ok) {
            unsigned short* orow = Whb + (size_t)row * OUT_FEAT;
#pragma unroll
            for (int nb = 0; nb < 8; ++nb) {
                float v = acc[nb][r];
                orow[nb * 16 + col0] = f2bf(v);
                p1 = fmaf(v, a1c[nb], p1);
                p2 = fmaf(v, a2c[nb], p2);
            }
        }
#pragma unroll
        for (int off = 8; off > 0; off >>= 1) {
            p1 += __shfl_xor(p1, off, 64);
            p2 += __shfl_xor(p2, off, 64);
        }
        if (ok && col0 == 0) {
            s1[row] = p1;
            s2[row] = p2;
        }
    }
}

// ---------------- K3: binB — bucket -> padded CSR ----------------

__global__ __launch_bounds__(256) void binB_kernel(const int* __restrict__ bucket_cursor,
                                                   const int* __restrict__ binned,
                                                   int* __restrict__ cnt,
                                                   int* __restrict__ csr) {
    __shared__ int cL[BNODES];
    int b = blockIdx.x;
    int t = threadIdx.x;
    if (t < BNODES) cL[t] = 0;
    __syncthreads();
    int m = min(bucket_cursor[b], BCAP);
    const int* bp = binned + (size_t)b * BCAP;
    int n0 = b * BNODES;
    for (int i = t; i < m; i += 256) {
        int p = bp[i];
        int sl = p >> 16;
        int d = p & 0xFFFF;
        int pos = atomicAdd(&cL[sl], 1);
        if (pos < PAD_DEG) csr[(size_t)(n0 + sl) * PAD_DEG + pos] = d;
    }
    __syncthreads();
    if (t < BNODES) cnt[n0 + t] = min(cL[t], PAD_DEG);
}

// ---------------- K4: per-node softmax + aggregation ----------------

__global__ __launch_bounds__(256) void node_kernel(const unsigned short* __restrict__ Whb,
                                                   const float* __restrict__ s1,
                                                   const float* __restrict__ s2,
                                                   const int* __restrict__ cnt,
                                                   const int* __restrict__ csr,
                                                   float* __restrict__ out) {
    int lane = threadIdx.x & 63;
    int w = threadIdx.x >> 6;
    int n = blockIdx.x * 4 + w;
    if (n >= N_NODES) return;
    int deg = cnt[n];
    size_t start = (size_t)n * PAD_DEG;
    int g = lane >> 4;
    int fo = lane & 15;

    float accv[8];
#pragma unroll
    for (int f = 0; f < 8; ++f) accv[f] = 0.f;
    float inv = 0.f;

    if (deg > 0) {
        float s1n = s1[n];
        int d0 = 0, d1 = 0;
        float ex0 = 0.f, ex1 = 0.f;
        if (lane < deg) {
            d0 = csr[start + lane];
            float ev = s1n + s2[d0];
            ev = ev >= 0.f ? ev : NEG_SLOPE * ev;
            ex0 = __expf(ev * INV_TEMP);
        }
        if (lane + 64 < deg) {
            d1 = csr[start + lane + 64];
            float ev = s1n + s2[d1];
            ev = ev >= 0.f ? ev : NEG_SLOPE * ev;
            ex1 = __expf(ev * INV_TEMP);
        }
        float denom = ex0 + ex1;
#pragma unroll
        for (int off = 32; off > 0; off >>= 1) denom += __shfl_xor(denom, off, 64);
        inv = 1.0f / denom;

#pragma unroll 2
        for (int jj = 0; jj < deg; jj += 8) {
            int e0 = jj + g;
            int e1 = jj + 4 + g;
            bool hi0 = jj >= 64;                 // wave-uniform
            bool hi1 = (jj + 4) >= 64;           // wave-uniform
            float p0 = __shfl(hi0 ? ex1 : ex0, e0 & 63, 64);
            int dd0 = __shfl(hi0 ? d1 : d0, e0 & 63, 64);
            float p1 = __shfl(hi1 ? ex1 : ex0, e1 & 63, 64);
            int dd1 = __shfl(hi1 ? d1 : d0, e1 & 63, 64);
            short8 row0 = *(const short8*)(Whb + (size_t)dd0 * OUT_FEAT + fo * 8);
            short8 row1 = *(const short8*)(Whb + (size_t)dd1 * OUT_FEAT + fo * 8);
#pragma unroll
            for (int f = 0; f < 8; ++f)
                accv[f] = fmaf(p0, bf2f((unsigned short)row0[f]), accv[f]);
#pragma unroll
            for (int f = 0; f < 8; ++f)
                accv[f] = fmaf(p1, bf2f((unsigned short)row1[f]), accv[f]);
        }
#pragma unroll
        for (int f = 0; f < 8; ++f) {
            accv[f] += __shfl_xor(accv[f], 16, 64);
            accv[f] += __shfl_xor(accv[f], 32, 64);
        }
    }

    if (g == 0) {
        float* orow = out + (size_t)n * OUT_FEAT + fo * 8;
        float4 o0, o1;
        o0.x = fmaxf(accv[0] * inv, 0.f); o0.y = fmaxf(accv[1] * inv, 0.f);
        o0.z = fmaxf(accv[2] * inv, 0.f); o0.w = fmaxf(accv[3] * inv, 0.f);
        o1.x = fmaxf(accv[4] * inv, 0.f); o1.y = fmaxf(accv[5] * inv, 0.f);
        o1.z = fmaxf(accv[6] * inv, 0.f); o1.w = fmaxf(accv[7] * inv, 0.f);
        *(float4*)(orow) = o0;
        *(float4*)(orow + 4) = o1;
    }
}

// ---------------- launch ----------------

extern "C" void kernel_launch(void* const* d_in, const int* in_sizes, int n_in,
                              void* d_out, int out_size, void* d_ws, size_t ws_size,
                              hipStream_t stream) {
    const float* h = (const float*)d_in[0];
    const float* W = (const float*)d_in[1];
    const float* a = (const float*)d_in[2];
    const int* edge = (const int*)d_in[3];
    const int* src = edge;
    const int* dst = edge + N_EDGES;
    float* out = (float*)d_out;

    char* ws = (char*)d_ws;
    size_t off = 0;
    auto alloc = [&](size_t bytes) -> void* {
        void* p = ws + off;
        off = (off + bytes + 255) & ~(size_t)255;
        return p;
    };
    unsigned short* Whb = (unsigned short*)alloc((size_t)N_NODES * OUT_FEAT * sizeof(unsigned short));
    float* s1 = (float*)alloc((size_t)N_NODES * sizeof(float));
    float* s2 = (float*)alloc((size_t)N_NODES * sizeof(float));
    int* cnt = (int*)alloc((size_t)N_NODES * sizeof(int));
    int* csr = (int*)alloc((size_t)N_NODES * PAD_DEG * sizeof(int));
    unsigned short* Wt = (unsigned short*)alloc((size_t)IN_FEAT * OUT_FEAT * sizeof(unsigned short));
    int* bucket_cursor = (int*)alloc((size_t)BUCKETS * sizeof(int));
    int* binned = (int*)alloc((size_t)BUCKETS * BCAP * sizeof(int));

    convw_kernel<<<CONV_BLOCKS, 256, 0, stream>>>(W, Wt, bucket_cursor);
    gemm_binA_kernel<<<GEMM_BLOCKS + A_BLOCKS, 512, 0, stream>>>(h, Wt, a, Whb, s1, s2,
                                                                 src, dst, bucket_cursor, binned);
    binB_kernel<<<BUCKETS, 256, 0, stream>>>(bucket_cursor, binned, cnt, csr);
    node_kernel<<<(N_NODES + 3) / 4, 256, 0, stream>>>(Whb, s1, s2, cnt, csr, out);
}

// Round 10
// 241.370 us; speedup vs baseline: 1.2815x; 1.0133x over previous
//
#include <hip/hip_runtime.h>
#include <cstdint>
#include <cstddef>

#define N_NODES 50000
#define N_EDGES 1600000
#define IN_FEAT 512
#define OUT_FEAT 128
#define NEG_SLOPE 0.01f
#define INV_TEMP 2.0f
#define PAD_DEG 128     // P(Poisson(32) >= 128) ~ e^-81: never

// two-phase CSR build
#define BUCKETS 400
#define BNODES 125      // nodes per bucket (400*125 = 50000)
#define BCAP 5000       // bucket capacity; Poisson(4000) max over 400 ~ 4300
#define A_BLOCKS 500
#define A_EPC (N_EDGES / A_BLOCKS)   // 3200 edges per block
#define A_G4 (A_EPC / 4)             // 800 int4 groups

#define CONV_BLOCKS ((IN_FEAT * OUT_FEAT) / 256)   // 256
#define GEMM_BLOCKS ((N_NODES + 127) / 128)        // 391 (tile 128x128, 8 waves)

typedef __attribute__((ext_vector_type(8))) short short8;
typedef __attribute__((ext_vector_type(4))) float f32x4;

#define GLOBAL_AS __attribute__((address_space(1)))
#define LDS_AS __attribute__((address_space(3)))

__device__ inline unsigned short f2bf(float x) {
    unsigned int u = __float_as_uint(x);
    unsigned int r = (u + 0x7fffu + ((u >> 16) & 1u)) >> 16;
    return (unsigned short)r;
}
__device__ inline float bf2f(unsigned short b) {
    return __uint_as_float(((unsigned int)b) << 16);
}

// ---------------- K1: convert_w + zero bucket cursors ----------------

__global__ __launch_bounds__(256) void convw_kernel(const float* __restrict__ W,
                                                    unsigned short* __restrict__ Wt,
                                                    int* __restrict__ bucket_cursor) {
    int tid = blockIdx.x * 256 + threadIdx.x;
    if (tid < BUCKETS) bucket_cursor[tid] = 0;
    if (tid < IN_FEAT * OUT_FEAT) {
        int n = tid >> 9;
        int k = tid & 511;
        Wt[tid] = f2bf(W[k * OUT_FEAT + n]);
    }
}

// ---------------- K2: fused {mfma_gemm, binA} (proven: 60.1us) ----------------

__global__ __launch_bounds__(512) void gemm_binA_kernel(const float* __restrict__ h,
                                                        const unsigned short* __restrict__ Wt,
                                                        const float* __restrict__ a_vec,
                                                        unsigned short* __restrict__ Whb,
                                                        float* __restrict__ s1,
                                                        float* __restrict__ s2,
                                                        const int* __restrict__ src,
                                                        const int* __restrict__ dst,
                                                        int* __restrict__ bucket_cursor,
                                                        int* __restrict__ binned) {
    __shared__ unsigned short lB[3][8 * 2 * 64 * 8];   // 48 KB (gemm); binA aliases front 3.2KB

    if (blockIdx.x >= GEMM_BLOCKS) {
        // ---- binA role: bin edges by bucket (512-thread strides)
        int* cntL = (int*)&lB[0][0];
        int* baseL = cntL + BUCKETS;
        int t = threadIdx.x;
        for (int i = t; i < BUCKETS; i += 512) cntL[i] = 0;
        __syncthreads();
        size_t ebase = (size_t)(blockIdx.x - GEMM_BLOCKS) * A_EPC;

        for (int g = t; g < A_G4; g += 512) {
            int4 s4 = *(const int4*)(src + ebase + (size_t)g * 4);
#pragma unroll
            for (int j = 0; j < 4; ++j) {
                int s = (&s4.x)[j];
                atomicAdd(&cntL[s / BNODES], 1);
            }
        }
        __syncthreads();
        for (int i = t; i < BUCKETS; i += 512) {
            int c = cntL[i];
            baseL[i] = c ? atomicAdd(&bucket_cursor[i], c) : 0;
            cntL[i] = 0;
        }
        __syncthreads();
        for (int g = t; g < A_G4; g += 512) {
            int4 s4 = *(const int4*)(src + ebase + (size_t)g * 4);
            int4 d4 = *(const int4*)(dst + ebase + (size_t)g * 4);
#pragma unroll
            for (int j = 0; j < 4; ++j) {
                int s = (&s4.x)[j];
                int b = s / BNODES;
                int sl = s - b * BNODES;
                int pos = atomicAdd(&cntL[b], 1);
                int slot = baseL[b] + pos;
                if (slot < BCAP)
                    binned[(size_t)b * BCAP + slot] = (sl << 16) | (&d4.x)[j];
            }
        }
        return;
    }

    // ---- gemm role: tile 128x128, 8 waves (16 rows each), BK=64
    int bid = blockIdx.x;
    int t = threadIdx.x;
    int w = t >> 6;          // 0..7
    int L = t & 63;
    int m0 = bid * 128;

    int arow = m0 + w * 16 + (L & 15);
    int arow_c = arow < N_NODES ? arow : N_NODES - 1;   // clamp: loads unconditional
    int kq = (L >> 4) * 8;
    const float* arp = h + (size_t)arow_c * IN_FEAT + kq;

    f32x4 acc[8];
#pragma unroll
    for (int i = 0; i < 8; ++i) acc[i] = (f32x4){0.f, 0.f, 0.f, 0.f};

    auto stageB = [&](int slot, int k0) {
#pragma unroll
        for (int ksub = 0; ksub < 2; ++ksub) {
            const GLOBAL_AS unsigned short* g =
                (const GLOBAL_AS unsigned short*)(Wt + (size_t)(w * 16 + (L & 15)) * IN_FEAT +
                                                  (k0 + ksub * 32 + kq));
            LDS_AS unsigned short* lp = (LDS_AS unsigned short*)(&lB[slot][(w * 2 + ksub) * 512]);
            __builtin_amdgcn_global_load_lds((const GLOBAL_AS void*)g, (LDS_AS void*)lp, 16, 0, 0);
        }
    };
    auto loadA = [&](int step, float4 out[4]) {
        const float* p = arp + step * 64;
        out[0] = *(const float4*)(p);
        out[1] = *(const float4*)(p + 4);
        out[2] = *(const float4*)(p + 32);
        out[3] = *(const float4*)(p + 36);
    };
    auto convA = [&](const float4 a[4], short8& f0, short8& f1) {
        short8 v;
        v[0] = (short)f2bf(a[0].x); v[1] = (short)f2bf(a[0].y);
        v[2] = (short)f2bf(a[0].z); v[3] = (short)f2bf(a[0].w);
        v[4] = (short)f2bf(a[1].x); v[5] = (short)f2bf(a[1].y);
        v[6] = (short)f2bf(a[1].z); v[7] = (short)f2bf(a[1].w);
        f0 = v;
        v[0] = (short)f2bf(a[2].x); v[1] = (short)f2bf(a[2].y);
        v[2] = (short)f2bf(a[2].z); v[3] = (short)f2bf(a[2].w);
        v[4] = (short)f2bf(a[3].x); v[5] = (short)f2bf(a[3].y);
        v[6] = (short)f2bf(a[3].z); v[7] = (short)f2bf(a[3].w);
        f1 = v;
    };

    float4 avA[4], avB[4], avC[4];
#pragma unroll
    for (int q = 0; q < 4; ++q) avC[q] = make_float4(0.f, 0.f, 0.f, 0.f);

    stageB(0, 0);
    asm volatile("" ::: "memory");   // pin: stage(0) oldest in vmcnt order
    stageB(1, 64);
    loadA(0, avA);
    loadA(1, avB);
    asm volatile("s_waitcnt vmcnt(10)" ::: "memory");
    __builtin_amdgcn_s_barrier();

#pragma unroll
    for (int it = 0; it < 8; ++it) {
        if (it < 6) {
            stageB((it + 2) % 3, (it + 2) * 64);   // 2 VMEM
            loadA(it + 2, avC);                    // 4 VMEM
        }

        short8 af0, af1;
        convA(avA, af0, af1);

        const int buf = it % 3;
#pragma unroll
        for (int nb = 0; nb < 8; ++nb) {
            short8 bf = *(const short8*)(&lB[buf][((nb * 2 + 0) * 64 + L) * 8]);
            acc[nb] = __builtin_amdgcn_mfma_f32_16x16x32_bf16(af0, bf, acc[nb], 0, 0, 0);
        }
#pragma unroll
        for (int nb = 0; nb < 8; ++nb) {
            short8 bf = *(const short8*)(&lB[buf][((nb * 2 + 1) * 64 + L) * 8]);
            acc[nb] = __builtin_amdgcn_mfma_f32_16x16x32_bf16(af1, bf, acc[nb], 0, 0, 0);
        }

#pragma unroll
        for (int q = 0; q < 4; ++q) { avA[q] = avB[q]; avB[q] = avC[q]; }

        if (it < 6) {
            asm volatile("s_waitcnt vmcnt(6)" ::: "memory");
            __builtin_amdgcn_s_barrier();
        } else if (it == 6) {
            asm volatile("s_waitcnt vmcnt(0)" ::: "memory");
            __builtin_amdgcn_s_barrier();
        }
    }

    int col0 = L & 15;
    int rbase = m0 + w * 16 + (L >> 4) * 4;

    float a1c[8], a2c[8];
#pragma unroll
    for (int nb = 0; nb < 8; ++nb) {
        a1c[nb] = a_vec[nb * 16 + col0];
        a2c[nb] = a_vec[128 + nb * 16 + col0];
    }

#pragma unroll
    for (int r = 0; r < 4; ++r) {
        int row = rbase + r;
        bool ok = row < N_NODES;
        float p1 = 0.f, p2 = 0.f;
        if (ok) {
            unsigned short* orow = Whb + (size_t)row * OUT_FEAT;
#pragma unroll
            for (int nb = 0; nb < 8; ++nb) {
                float v = acc[nb][r];
                orow[nb * 16 + col0] = f2bf(v);
                p1 = fmaf(v, a1c[nb], p1);
                p2 = fmaf(v, a2c[nb], p2);
            }
        }
#pragma unroll
        for (int off = 8; off > 0; off >>= 1) {
            p1 += __shfl_xor(p1, off, 64);
            p2 += __shfl_xor(p2, off, 64);
        }
        if (ok && col0 == 0) {
            s1[row] = p1;
            s2[row] = p2;
        }
    }
}

// ---------------- K3: fused {binB scatter -> LDS CSR, node softmax+agg} ----
// One block per bucket (400 blocks x 512 thr). Phase 1: scatter this
// bucket's binned entries into an LDS csr (ushort: dst < 65536; 125x128x2B
// = 32KB -> ~4 blocks/CU, occupancy preserved). Phase 2: 8 waves run the
// proven per-wave node body for the bucket's 125 nodes, csr/deg from LDS.
// Removes: binB dispatch (~25us serial), 51MB csr HBM round-trip, one
// launch gap. Cross-block overlap: block b's gathers hide block b+1's
// scatter.

__global__ __launch_bounds__(512) void binB_node_kernel(const unsigned short* __restrict__ Whb,
                                                        const float* __restrict__ s1,
                                                        const float* __restrict__ s2,
                                                        const int* __restrict__ bucket_cursor,
                                                        const int* __restrict__ binned,
                                                        float* __restrict__ out) {
    __shared__ int cL[BNODES];                                // 500 B
    __shared__ unsigned short csrL[BNODES * PAD_DEG];         // 32000 B
    int b = blockIdx.x;
    int t = threadIdx.x;
    int n0 = b * BNODES;

    // ---- phase 1: bucket -> LDS csr
    if (t < BNODES) cL[t] = 0;
    __syncthreads();
    int m = min(bucket_cursor[b], BCAP);
    const int* bp = binned + (size_t)b * BCAP;
    for (int i = t; i < m; i += 512) {
        int p = bp[i];
        int sl = p >> 16;
        int d = p & 0xFFFF;
        int pos = atomicAdd(&cL[sl], 1);
        if (pos < PAD_DEG) csrL[sl * PAD_DEG + pos] = (unsigned short)d;
    }
    __syncthreads();

    // ---- phase 2: per-node softmax + aggregation (wave w: nodes w, w+8, ...)
    int lane = t & 63;
    int w = t >> 6;
    int g = lane >> 4;
    int fo = lane & 15;

    for (int sl = w; sl < BNODES; sl += 8) {
        int n = n0 + sl;
        int deg = min(cL[sl], PAD_DEG);
        const unsigned short* crow = &csrL[sl * PAD_DEG];

        float accv[8];
#pragma unroll
        for (int f = 0; f < 8; ++f) accv[f] = 0.f;
        float inv = 0.f;

        if (deg > 0) {
            float s1n = s1[n];
            int d0 = 0, d1 = 0;
            float ex0 = 0.f, ex1 = 0.f;
            if (lane < deg) {
                d0 = crow[lane];
                float ev = s1n + s2[d0];
                ev = ev >= 0.f ? ev : NEG_SLOPE * ev;
                ex0 = __expf(ev * INV_TEMP);
            }
            if (lane + 64 < deg) {
                d1 = crow[lane + 64];
                float ev = s1n + s2[d1];
                ev = ev >= 0.f ? ev : NEG_SLOPE * ev;
                ex1 = __expf(ev * INV_TEMP);
            }
            float denom = ex0 + ex1;
#pragma unroll
            for (int off = 32; off > 0; off >>= 1) denom += __shfl_xor(denom, off, 64);
            inv = 1.0f / denom;

#pragma unroll 2
            for (int jj = 0; jj < deg; jj += 8) {
                int e0 = jj + g;
                int e1 = jj + 4 + g;
                bool hi0 = jj >= 64;                 // wave-uniform
                bool hi1 = (jj + 4) >= 64;           // wave-uniform
                float p0 = __shfl(hi0 ? ex1 : ex0, e0 & 63, 64);
                int dd0 = __shfl(hi0 ? d1 : d0, e0 & 63, 64);
                float p1 = __shfl(hi1 ? ex1 : ex0, e1 & 63, 64);
                int dd1 = __shfl(hi1 ? d1 : d0, e1 & 63, 64);
                short8 row0 = *(const short8*)(Whb + (size_t)dd0 * OUT_FEAT + fo * 8);
                short8 row1 = *(const short8*)(Whb + (size_t)dd1 * OUT_FEAT + fo * 8);
#pragma unroll
                for (int f = 0; f < 8; ++f)
                    accv[f] = fmaf(p0, bf2f((unsigned short)row0[f]), accv[f]);
#pragma unroll
                for (int f = 0; f < 8; ++f)
                    accv[f] = fmaf(p1, bf2f((unsigned short)row1[f]), accv[f]);
            }
#pragma unroll
            for (int f = 0; f < 8; ++f) {
                accv[f] += __shfl_xor(accv[f], 16, 64);
                accv[f] += __shfl_xor(accv[f], 32, 64);
            }
        }

        if (g == 0) {
            float* orow = out + (size_t)n * OUT_FEAT + fo * 8;
            float4 o0, o1;
            o0.x = fmaxf(accv[0] * inv, 0.f); o0.y = fmaxf(accv[1] * inv, 0.f);
            o0.z = fmaxf(accv[2] * inv, 0.f); o0.w = fmaxf(accv[3] * inv, 0.f);
            o1.x = fmaxf(accv[4] * inv, 0.f); o1.y = fmaxf(accv[5] * inv, 0.f);
            o1.z = fmaxf(accv[6] * inv, 0.f); o1.w = fmaxf(accv[7] * inv, 0.f);
            *(float4*)(orow) = o0;
            *(float4*)(orow + 4) = o1;
        }
    }
}

// ---------------- launch ----------------

extern "C" void kernel_launch(void* const* d_in, const int* in_sizes, int n_in,
                              void* d_out, int out_size, void* d_ws, size_t ws_size,
                              hipStream_t stream) {
    const float* h = (const float*)d_in[0];
    const float* W = (const float*)d_in[1];
    const float* a = (const float*)d_in[2];
    const int* edge = (const int*)d_in[3];
    const int* src = edge;
    const int* dst = edge + N_EDGES;
    float* out = (float*)d_out;

    char* ws = (char*)d_ws;
    size_t off = 0;
    auto alloc = [&](size_t bytes) -> void* {
        void* p = ws + off;
        off = (off + bytes + 255) & ~(size_t)255;
        return p;
    };
    unsigned short* Whb = (unsigned short*)alloc((size_t)N_NODES * OUT_FEAT * sizeof(unsigned short));
    float* s1 = (float*)alloc((size_t)N_NODES * sizeof(float));
    float* s2 = (float*)alloc((size_t)N_NODES * sizeof(float));
    unsigned short* Wt = (unsigned short*)alloc((size_t)IN_FEAT * OUT_FEAT * sizeof(unsigned short));
    int* bucket_cursor = (int*)alloc((size_t)BUCKETS * sizeof(int));
    int* binned = (int*)alloc((size_t)BUCKETS * BCAP * sizeof(int));

    convw_kernel<<<CONV_BLOCKS, 256, 0, stream>>>(W, Wt, bucket_cursor);
    gemm_binA_kernel<<<GEMM_BLOCKS + A_BLOCKS, 512, 0, stream>>>(h, Wt, a, Whb, s1, s2,
                                                                 src, dst, bucket_cursor, binned);
    binB_node_kernel<<<BUCKETS, 512, 0, stream>>>(Whb, s1, s2, bucket_cursor, binned, out);
}

// Round 11
// 236.991 us; speedup vs baseline: 1.3051x; 1.0185x over previous
//
#include <hip/hip_runtime.h>
#include <cstdint>
#include <cstddef>

#define N_NODES 50000
#define N_EDGES 1600000
#define IN_FEAT 512
#define OUT_FEAT 128
#define NEG_SLOPE 0.01f
#define INV_TEMP 2.0f
#define PAD_DEG 128     // P(Poisson(32) >= 128) ~ e^-81: never

// two-phase CSR build
#define BUCKETS 400
#define BNODES 125      // nodes per bucket (400*125 = 50000)
#define BCAP 5000       // bucket capacity; Poisson(4000) max over 400 ~ 4300
#define A_BLOCKS 500
#define A_EPC (N_EDGES / A_BLOCKS)   // 3200 edges per block
#define A_G4 (A_EPC / 4)             // 800 int4 groups

#define CONV_BLOCKS ((IN_FEAT * OUT_FEAT) / 256)   // 256
#define GEMM_BLOCKS ((N_NODES + 127) / 128)        // 391 (tile 128x128, 8 waves)

typedef __attribute__((ext_vector_type(8))) short short8;
typedef __attribute__((ext_vector_type(4))) float f32x4;

#define GLOBAL_AS __attribute__((address_space(1)))
#define LDS_AS __attribute__((address_space(3)))

__device__ inline unsigned short f2bf(float x) {
    unsigned int u = __float_as_uint(x);
    unsigned int r = (u + 0x7fffu + ((u >> 16) & 1u)) >> 16;
    return (unsigned short)r;
}
__device__ inline float bf2f(unsigned short b) {
    return __uint_as_float(((unsigned int)b) << 16);
}

// ---------------- K1: convert_w + zero bucket cursors ----------------

__global__ __launch_bounds__(256) void convw_kernel(const float* __restrict__ W,
                                                    unsigned short* __restrict__ Wt,
                                                    int* __restrict__ bucket_cursor) {
    int tid = blockIdx.x * 256 + threadIdx.x;
    if (tid < BUCKETS) bucket_cursor[tid] = 0;
    if (tid < IN_FEAT * OUT_FEAT) {
        int n = tid >> 9;
        int k = tid & 511;
        Wt[tid] = f2bf(W[k * OUT_FEAT + n]);
    }
}

// ---------------- K2: fused {mfma_gemm, binA} (proven: 60.1us) ----------------

__global__ __launch_bounds__(512) void gemm_binA_kernel(const float* __restrict__ h,
                                                        const unsigned short* __restrict__ Wt,
                                                        const float* __restrict__ a_vec,
                                                        unsigned short* __restrict__ Whb,
                                                        float* __restrict__ s1,
                                                        float* __restrict__ s2,
                                                        const int* __restrict__ src,
                                                        const int* __restrict__ dst,
                                                        int* __restrict__ bucket_cursor,
                                                        int* __restrict__ binned) {
    __shared__ unsigned short lB[3][8 * 2 * 64 * 8];   // 48 KB (gemm); binA aliases front 3.2KB

    if (blockIdx.x >= GEMM_BLOCKS) {
        // ---- binA role: bin edges by bucket (512-thread strides)
        int* cntL = (int*)&lB[0][0];
        int* baseL = cntL + BUCKETS;
        int t = threadIdx.x;
        for (int i = t; i < BUCKETS; i += 512) cntL[i] = 0;
        __syncthreads();
        size_t ebase = (size_t)(blockIdx.x - GEMM_BLOCKS) * A_EPC;

        for (int g = t; g < A_G4; g += 512) {
            int4 s4 = *(const int4*)(src + ebase + (size_t)g * 4);
#pragma unroll
            for (int j = 0; j < 4; ++j) {
                int s = (&s4.x)[j];
                atomicAdd(&cntL[s / BNODES], 1);
            }
        }
        __syncthreads();
        for (int i = t; i < BUCKETS; i += 512) {
            int c = cntL[i];
            baseL[i] = c ? atomicAdd(&bucket_cursor[i], c) : 0;
            cntL[i] = 0;
        }
        __syncthreads();
        for (int g = t; g < A_G4; g += 512) {
            int4 s4 = *(const int4*)(src + ebase + (size_t)g * 4);
            int4 d4 = *(const int4*)(dst + ebase + (size_t)g * 4);
#pragma unroll
            for (int j = 0; j < 4; ++j) {
                int s = (&s4.x)[j];
                int b = s / BNODES;
                int sl = s - b * BNODES;
                int pos = atomicAdd(&cntL[b], 1);
                int slot = baseL[b] + pos;
                if (slot < BCAP)
                    binned[(size_t)b * BCAP + slot] = (sl << 16) | (&d4.x)[j];
            }
        }
        return;
    }

    // ---- gemm role: tile 128x128, 8 waves (16 rows each), BK=64
    int bid = blockIdx.x;
    int t = threadIdx.x;
    int w = t >> 6;          // 0..7
    int L = t & 63;
    int m0 = bid * 128;

    int arow = m0 + w * 16 + (L & 15);
    int arow_c = arow < N_NODES ? arow : N_NODES - 1;   // clamp: loads unconditional
    int kq = (L >> 4) * 8;
    const float* arp = h + (size_t)arow_c * IN_FEAT + kq;

    f32x4 acc[8];
#pragma unroll
    for (int i = 0; i < 8; ++i) acc[i] = (f32x4){0.f, 0.f, 0.f, 0.f};

    auto stageB = [&](int slot, int k0) {
#pragma unroll
        for (int ksub = 0; ksub < 2; ++ksub) {
            const GLOBAL_AS unsigned short* g =
                (const GLOBAL_AS unsigned short*)(Wt + (size_t)(w * 16 + (L & 15)) * IN_FEAT +
                                                  (k0 + ksub * 32 + kq));
            LDS_AS unsigned short* lp = (LDS_AS unsigned short*)(&lB[slot][(w * 2 + ksub) * 512]);
            __builtin_amdgcn_global_load_lds((const GLOBAL_AS void*)g, (LDS_AS void*)lp, 16, 0, 0);
        }
    };
    auto loadA = [&](int step, float4 out[4]) {
        const float* p = arp + step * 64;
        out[0] = *(const float4*)(p);
        out[1] = *(const float4*)(p + 4);
        out[2] = *(const float4*)(p + 32);
        out[3] = *(const float4*)(p + 36);
    };
    auto convA = [&](const float4 a[4], short8& f0, short8& f1) {
        short8 v;
        v[0] = (short)f2bf(a[0].x); v[1] = (short)f2bf(a[0].y);
        v[2] = (short)f2bf(a[0].z); v[3] = (short)f2bf(a[0].w);
        v[4] = (short)f2bf(a[1].x); v[5] = (short)f2bf(a[1].y);
        v[6] = (short)f2bf(a[1].z); v[7] = (short)f2bf(a[1].w);
        f0 = v;
        v[0] = (short)f2bf(a[2].x); v[1] = (short)f2bf(a[2].y);
        v[2] = (short)f2bf(a[2].z); v[3] = (short)f2bf(a[2].w);
        v[4] = (short)f2bf(a[3].x); v[5] = (short)f2bf(a[3].y);
        v[6] = (short)f2bf(a[3].z); v[7] = (short)f2bf(a[3].w);
        f1 = v;
    };

    float4 avA[4], avB[4], avC[4];
#pragma unroll
    for (int q = 0; q < 4; ++q) avC[q] = make_float4(0.f, 0.f, 0.f, 0.f);

    stageB(0, 0);
    asm volatile("" ::: "memory");   // pin: stage(0) oldest in vmcnt order
    stageB(1, 64);
    loadA(0, avA);
    loadA(1, avB);
    asm volatile("s_waitcnt vmcnt(10)" ::: "memory");
    __builtin_amdgcn_s_barrier();

#pragma unroll
    for (int it = 0; it < 8; ++it) {
        if (it < 6) {
            stageB((it + 2) % 3, (it + 2) * 64);   // 2 VMEM
            loadA(it + 2, avC);                    // 4 VMEM
        }

        short8 af0, af1;
        convA(avA, af0, af1);

        const int buf = it % 3;
#pragma unroll
        for (int nb = 0; nb < 8; ++nb) {
            short8 bf = *(const short8*)(&lB[buf][((nb * 2 + 0) * 64 + L) * 8]);
            acc[nb] = __builtin_amdgcn_mfma_f32_16x16x32_bf16(af0, bf, acc[nb], 0, 0, 0);
        }
#pragma unroll
        for (int nb = 0; nb < 8; ++nb) {
            short8 bf = *(const short8*)(&lB[buf][((nb * 2 + 1) * 64 + L) * 8]);
            acc[nb] = __builtin_amdgcn_mfma_f32_16x16x32_bf16(af1, bf, acc[nb], 0, 0, 0);
        }

#pragma unroll
        for (int q = 0; q < 4; ++q) { avA[q] = avB[q]; avB[q] = avC[q]; }

        if (it < 6) {
            asm volatile("s_waitcnt vmcnt(6)" ::: "memory");
            __builtin_amdgcn_s_barrier();
        } else if (it == 6) {
            asm volatile("s_waitcnt vmcnt(0)" ::: "memory");
            __builtin_amdgcn_s_barrier();
        }
    }

    int col0 = L & 15;
    int rbase = m0 + w * 16 + (L >> 4) * 4;

    float a1c[8], a2c[8];
#pragma unroll
    for (int nb = 0; nb < 8; ++nb) {
        a1c[nb] = a_vec[nb * 16 + col0];
        a2c[nb] = a_vec[128 + nb * 16 + col0];
    }

#pragma unroll
    for (int r = 0; r < 4; ++r) {
        int row = rbase + r;
        bool ok = row < N_NODES;
        float p1 = 0.f, p2 = 0.f;
        if (ok) {
            unsigned short* orow = Whb + (size_t)row * OUT_FEAT;
#pragma unroll
            for (int nb = 0; nb < 8; ++nb) {
                float v = acc[nb][r];
                orow[nb * 16 + col0] = f2bf(v);
                p1 = fmaf(v, a1c[nb], p1);
                p2 = fmaf(v, a2c[nb], p2);
            }
        }
#pragma unroll
        for (int off = 8; off > 0; off >>= 1) {
            p1 += __shfl_xor(p1, off, 64);
            p2 += __shfl_xor(p2, off, 64);
        }
        if (ok && col0 == 0) {
            s1[row] = p1;
            s2[row] = p2;
        }
    }
}

// ---------------- K3: fused {binB scatter -> LDS CSR, node softmax+agg} ----
// v2: 1024-thread blocks (16 waves). Round-10 counters showed Occupancy 27%
// — the 400-block grid gave only ~1.6 blocks/CU x 8 waves = ~12 waves/CU,
// starving the latency-laden gather loop of TLP. Same 400 blocks, double the
// waves: scatter strides 1024 (2x faster), each wave handles ~8 nodes
// (sl += 16). Thread cap allows 2 such blocks/CU; VGPR=32 -> no pressure.

__global__ __launch_bounds__(1024) void binB_node_kernel(const unsigned short* __restrict__ Whb,
                                                         const float* __restrict__ s1,
                                                         const float* __restrict__ s2,
                                                         const int* __restrict__ bucket_cursor,
                                                         const int* __restrict__ binned,
                                                         float* __restrict__ out) {
    __shared__ int cL[BNODES];                                // 500 B
    __shared__ unsigned short csrL[BNODES * PAD_DEG];         // 32000 B
    int b = blockIdx.x;
    int t = threadIdx.x;
    int n0 = b * BNODES;

    // ---- phase 1: bucket -> LDS csr
    if (t < BNODES) cL[t] = 0;
    __syncthreads();
    int m = min(bucket_cursor[b], BCAP);
    const int* bp = binned + (size_t)b * BCAP;
    for (int i = t; i < m; i += 1024) {
        int p = bp[i];
        int sl = p >> 16;
        int d = p & 0xFFFF;
        int pos = atomicAdd(&cL[sl], 1);
        if (pos < PAD_DEG) csrL[sl * PAD_DEG + pos] = (unsigned short)d;
    }
    __syncthreads();

    // ---- phase 2: per-node softmax + aggregation (wave w: nodes w, w+16, ...)
    int lane = t & 63;
    int w = t >> 6;          // 0..15
    int g = lane >> 4;
    int fo = lane & 15;

    for (int sl = w; sl < BNODES; sl += 16) {
        int n = n0 + sl;
        int deg = min(cL[sl], PAD_DEG);
        const unsigned short* crow = &csrL[sl * PAD_DEG];

        float accv[8];
#pragma unroll
        for (int f = 0; f < 8; ++f) accv[f] = 0.f;
        float inv = 0.f;

        if (deg > 0) {
            float s1n = s1[n];
            int d0 = 0, d1 = 0;
            float ex0 = 0.f, ex1 = 0.f;
            if (lane < deg) {
                d0 = crow[lane];
                float ev = s1n + s2[d0];
                ev = ev >= 0.f ? ev : NEG_SLOPE * ev;
                ex0 = __expf(ev * INV_TEMP);
            }
            if (lane + 64 < deg) {
                d1 = crow[lane + 64];
                float ev = s1n + s2[d1];
                ev = ev >= 0.f ? ev : NEG_SLOPE * ev;
                ex1 = __expf(ev * INV_TEMP);
            }
            float denom = ex0 + ex1;
#pragma unroll
            for (int off = 32; off > 0; off >>= 1) denom += __shfl_xor(denom, off, 64);
            inv = 1.0f / denom;

#pragma unroll 2
            for (int jj = 0; jj < deg; jj += 8) {
                int e0 = jj + g;
                int e1 = jj + 4 + g;
                bool hi0 = jj >= 64;                 // wave-uniform
                bool hi1 = (jj + 4) >= 64;           // wave-uniform
                float p0 = __shfl(hi0 ? ex1 : ex0, e0 & 63, 64);
                int dd0 = __shfl(hi0 ? d1 : d0, e0 & 63, 64);
                float p1 = __shfl(hi1 ? ex1 : ex0, e1 & 63, 64);
                int dd1 = __shfl(hi1 ? d1 : d0, e1 & 63, 64);
                short8 row0 = *(const short8*)(Whb + (size_t)dd0 * OUT_FEAT + fo * 8);
                short8 row1 = *(const short8*)(Whb + (size_t)dd1 * OUT_FEAT + fo * 8);
#pragma unroll
                for (int f = 0; f < 8; ++f)
                    accv[f] = fmaf(p0, bf2f((unsigned short)row0[f]), accv[f]);
#pragma unroll
                for (int f = 0; f < 8; ++f)
                    accv[f] = fmaf(p1, bf2f((unsigned short)row1[f]), accv[f]);
            }
#pragma unroll
            for (int f = 0; f < 8; ++f) {
                accv[f] += __shfl_xor(accv[f], 16, 64);
                accv[f] += __shfl_xor(accv[f], 32, 64);
            }
        }

        if (g == 0) {
            float* orow = out + (size_t)n * OUT_FEAT + fo * 8;
            float4 o0, o1;
            o0.x = fmaxf(accv[0] * inv, 0.f); o0.y = fmaxf(accv[1] * inv, 0.f);
            o0.z = fmaxf(accv[2] * inv, 0.f); o0.w = fmaxf(accv[3] * inv, 0.f);
            o1.x = fmaxf(accv[4] * inv, 0.f); o1.y = fmaxf(accv[5] * inv, 0.f);
            o1.z = fmaxf(accv[6] * inv, 0.f); o1.w = fmaxf(accv[7] * inv, 0.f);
            *(float4*)(orow) = o0;
            *(float4*)(orow + 4) = o1;
        }
    }
}

// ---------------- launch ----------------

extern "C" void kernel_launch(void* const* d_in, const int* in_sizes, int n_in,
                              void* d_out, int out_size, void* d_ws, size_t ws_size,
                              hipStream_t stream) {
    const float* h = (const float*)d_in[0];
    const float* W = (const float*)d_in[1];
    const float* a = (const float*)d_in[2];
    const int* edge = (const int*)d_in[3];
    const int* src = edge;
    const int* dst = edge + N_EDGES;
    float* out = (float*)d_out;

    char* ws = (char*)d_ws;
    size_t off = 0;
    auto alloc = [&](size_t bytes) -> void* {
        void* p = ws + off;
        off = (off + bytes + 255) & ~(size_t)255;
        return p;
    };
    unsigned short* Whb = (unsigned short*)alloc((size_t)N_NODES * OUT_FEAT * sizeof(unsigned short));
    float* s1 = (float*)alloc((size_t)N_NODES * sizeof(float));
    float* s2 = (float*)alloc((size_t)N_NODES * sizeof(float));
    unsigned short* Wt = (unsigned short*)alloc((size_t)IN_FEAT * OUT_FEAT * sizeof(unsigned short));
    int* bucket_cursor = (int*)alloc((size_t)BUCKETS * sizeof(int));
    int* binned = (int*)alloc((size_t)BUCKETS * BCAP * sizeof(int));

    convw_kernel<<<CONV_BLOCKS, 256, 0, stream>>>(W, Wt, bucket_cursor);
    gemm_binA_kernel<<<GEMM_BLOCKS + A_BLOCKS, 512, 0, stream>>>(h, Wt, a, Whb, s1, s2,
                                                                 src, dst, bucket_cursor, binned);
    binB_node_kernel<<<BUCKETS, 1024, 0, stream>>>(Whb, s1, s2, bucket_cursor, binned, out);
}